// Round 13
// baseline (176.228 us; speedup 1.0000x reference)
//
#include <hip/hip_runtime.h>
#include <math.h>

#define DM 768
#define NH 8
#define HD 96
#define BQ 4
#define LQ 1024
#define LK 4096
#define BH (BQ*NH)
#define KVS 4              // kv-split factor
#define KC (LK/KVS)        // keys per chunk = 1024
#define NT (KC/64)         // 64-key tiles per block = 16
#define QB 128             // q-rows per block (32 per wave)
#define NW (DM*DM)
#define NKSTEP (DM/64)     // 12 K-steps

typedef unsigned short ushort;
typedef unsigned int uint;
typedef __attribute__((ext_vector_type(8))) short short8v;
typedef __attribute__((ext_vector_type(4))) float float4v;

// 1/sqrt(96) * log2(e)  (folded into Q projection)
#define QSCALE 0.14724444641f

static __device__ __forceinline__ ushort f2bf(float x) {
    union { float f; uint u; } c; c.f = x;
    uint u = c.u;
    u += ((u >> 16) & 1u) + 0x7fffu;   // RNE
    return (ushort)(u >> 16);
}

static __device__ __forceinline__ float bf2f(ushort x) {
    union { uint u; float f; } c; c.u = (uint)x << 16;
    return c.f;
}

static __device__ __forceinline__ uint cvtpk(float lo, float hi) {
    uint d;
    asm("v_cvt_pk_bf16_f32 %0, %1, %2" : "=v"(d) : "v"(lo), "v"(hi));
    return d;
}

static __device__ __forceinline__ float exp2hw(float x) {
#if __has_builtin(__builtin_amdgcn_exp2f)
    return __builtin_amdgcn_exp2f(x);
#else
    return __expf(x * 0.6931471805599453f);
#endif
}

static __device__ __forceinline__ void gload_lds16(const void* g, void* l) {
    __builtin_amdgcn_global_load_lds(
        (const __attribute__((address_space(1))) uint*)g,
        (__attribute__((address_space(3))) uint*)l, 16, 0, 0);
}

// weights fp32 -> bf16 (4 matrices into contiguous dst), 4 elems/thread
__global__ __launch_bounds__(256)
void wcvt(const float* __restrict__ w0, const float* __restrict__ w1,
          const float* __restrict__ w2, const float* __restrict__ w3,
          ushort* __restrict__ d)
{
    const int SEG = NW / 1024;           // 576 blocks per matrix
    int b = blockIdx.x;
    int wsel = b / SEG, ib = b % SEG;
    const float* s = (wsel == 0) ? w0 : (wsel == 1) ? w1 : (wsel == 2) ? w2 : w3;
    int i = ib * 256 + threadIdx.x;
    float4 v = ((const float4*)s)[i];
    uint2 o;
    o.x = (uint)f2bf(v.x) | ((uint)f2bf(v.y) << 16);
    o.y = (uint)f2bf(v.z) | ((uint)f2bf(v.w) << 16);
    ((uint2*)(d + (size_t)wsel * NW))[i] = o;
}

// Fused QKV projection GEMM, 128x128 tile, DOUBLE-BUFFERED LDS, ONE barrier/K-step.
// Iter t: issue B(t+1)->DMA Bs[nxt], A(t+1)->regs; compute(cur); cvt+ds_write
// As[nxt]; barrier. Load latency spans the 32-MFMA compute phase (T3 2-phase).
// Segments: [0,192)=Q (RoPE), [192,960)=K (RoPE), [960,1728)=V (transpose).
__global__ __launch_bounds__(256, 2)
void qkv_gemm(const float* __restrict__ qf, const float* __restrict__ kf,
              const float* __restrict__ vf,
              const ushort* __restrict__ wqb, const ushort* __restrict__ wkb,
              const ushort* __restrict__ wvb,
              const float* __restrict__ bq, const float* __restrict__ bk,
              const float* __restrict__ bv,
              const float* __restrict__ cq, const float* __restrict__ ck,
              ushort* __restrict__ qws, ushort* __restrict__ kws,
              ushort* __restrict__ vtb)
{
    // 64 KB: As0=[0,16K) As1=[16K,32K) Bs0=[32K,48K) Bs1=[48K,64K) (bytes)
    __shared__ ushort Sh[32768];
    char* base = (char*)Sh;

    const int tid  = threadIdx.x;
    const int w    = tid >> 6;
    const int lane = tid & 63;
    const int l15  = lane & 15;
    const int lg   = lane >> 4;
    const int wm   = w >> 1, wn = w & 1;

    // segment decode (block-uniform)
    const int L = blockIdx.x;
    int seg, idx, Lshift, rpx;
    const float* X32; const ushort* Wbp; const float* bias; const float* coords;
    ushort* out; float oscale;
    if (L < 192)      { seg = 0; idx = L;       X32 = qf; Wbp = wqb; bias = bq; coords = cq; out = qws; Lshift = 10; rpx = 4;  oscale = QSCALE; }
    else if (L < 960) { seg = 1; idx = L - 192; X32 = kf; Wbp = wkb; bias = bk; coords = ck; out = kws; Lshift = 12; rpx = 16; oscale = 1.0f; }
    else              { seg = 2; idx = L - 960; X32 = vf; Wbp = wvb; bias = bv; coords = 0;  out = vtb; Lshift = 12; rpx = 16; oscale = 1.0f; }

    const int xcd  = idx & 7;
    const int sq   = idx >> 3;
    const int col0 = (sq % 6) * 128;
    const int row0 = (xcd * rpx + sq / 6) * 128;

    float4v acc[4][4];
    #pragma unroll
    for (int m = 0; m < 4; ++m)
        #pragma unroll
        for (int n = 0; n < 4; ++n) acc[m][n] = (float4v)0.f;

    // staging geometry (both operands): 4 chunks, 2-bit XOR swizzle
    int PA[4], rA[4], cA[4];
    #pragma unroll
    for (int c = 0; c < 4; ++c) {
        int P = ((w*4 + c) << 10) + lane*16;
        int lgc = P ^ (((P >> 9) & 3) << 5);
        PA[c] = P;
        rA[c] = lgc >> 7;
        cA[c] = (lgc & 127) >> 1;
    }
    const float*  xb = X32 + (size_t)row0 * DM;
    const ushort* wb = Wbp + (size_t)col0 * DM;

    int offA[2][4], offB[2][4];
    #pragma unroll
    for (int kk = 0; kk < 2; ++kk) {
        #pragma unroll
        for (int m = 0; m < 4; ++m) {
            int byte = (wm*64 + m*16 + l15)*128 + kk*64 + lg*16;
            offA[kk][m] = byte ^ (((byte >> 9) & 3) << 5);
            byte = (wn*64 + m*16 + l15)*128 + kk*64 + lg*16;
            offB[kk][m] = byte ^ (((byte >> 9) & 3) << 5);
        }
    }

    // ---- prologue: stage tile 0 into buf 0 ----
    float4 fa[4], fb[4];
    #pragma unroll
    for (int c = 0; c < 4; ++c) {
        const float* src = xb + (size_t)rA[c]*DM + cA[c];
        fa[c] = *(const float4*)src;
        fb[c] = *(const float4*)(src + 4);
    }
    #pragma unroll
    for (int c = 0; c < 4; ++c)
        gload_lds16(wb + (size_t)rA[c]*DM + cA[c], base + 32768 + PA[c]);
    #pragma unroll
    for (int c = 0; c < 4; ++c) {
        uint4 pk;
        pk.x = cvtpk(fa[c].x, fa[c].y);
        pk.y = cvtpk(fa[c].z, fa[c].w);
        pk.z = cvtpk(fb[c].x, fb[c].y);
        pk.w = cvtpk(fb[c].z, fb[c].w);
        *(uint4*)(base + PA[c]) = pk;
    }
    __syncthreads();

    for (int t = 0; t < NKSTEP; ++t) {
        const int cur = t & 1, nxt = cur ^ 1;
        char* Asc = base + cur*16384;
        char* Bsc = base + 32768 + cur*16384;
        if (t + 1 < NKSTEP) {
            const int kn = (t + 1) * 64;
            // issue next B -> DMA into Bs[nxt] (latency spans compute below)
            #pragma unroll
            for (int c = 0; c < 4; ++c)
                gload_lds16(wb + (size_t)rA[c]*DM + kn + cA[c],
                            base + 32768 + nxt*16384 + PA[c]);
            // issue next A -> regs
            #pragma unroll
            for (int c = 0; c < 4; ++c) {
                const float* src = xb + (size_t)rA[c]*DM + kn + cA[c];
                fa[c] = *(const float4*)src;
                fb[c] = *(const float4*)(src + 4);
            }
        }
        // compute tile t from buf[cur]
        #pragma unroll
        for (int kk = 0; kk < 2; ++kk) {
            short8v af[4], bfm[4];
            #pragma unroll
            for (int m = 0; m < 4; ++m)
                af[m] = *(const short8v*)(Asc + offA[kk][m]);
            #pragma unroll
            for (int n = 0; n < 4; ++n)
                bfm[n] = *(const short8v*)(Bsc + offB[kk][n]);
            #pragma unroll
            for (int m = 0; m < 4; ++m)
                #pragma unroll
                for (int n = 0; n < 4; ++n)
                    acc[m][n] = __builtin_amdgcn_mfma_f32_16x16x32_bf16(af[m], bfm[n], acc[m][n], 0, 0, 0);
        }
        // publish next A into As[nxt] (A-load waitcnt sinks past the MFMAs)
        if (t + 1 < NKSTEP) {
            #pragma unroll
            for (int c = 0; c < 4; ++c) {
                uint4 pk;
                pk.x = cvtpk(fa[c].x, fa[c].y);
                pk.y = cvtpk(fa[c].z, fa[c].w);
                pk.z = cvtpk(fb[c].x, fb[c].y);
                pk.w = cvtpk(fb[c].z, fb[c].w);
                *(uint4*)(base + nxt*16384 + PA[c]) = pk;
            }
        }
        __syncthreads();   // single barrier: drains B-DMA + A ds_writes, syncs reads
    }

    const int colbase = col0 + wn*64;
    float bvv[4];
    #pragma unroll
    for (int nt = 0; nt < 4; ++nt) bvv[nt] = bias[colbase + nt*16 + l15];
    #pragma unroll
    for (int m = 0; m < 4; ++m)
        #pragma unroll
        for (int nt = 0; nt < 4; ++nt)
            #pragma unroll
            for (int r = 0; r < 4; ++r) acc[m][nt][r] += bvv[nt];

    if (seg < 2) {
        // RoPE + bf16 (B,NH,L,96) store
        const float freq = exp2f(-(float)l15 * 0.83048202372184058696f);
        const int a0 = ((colbase >> 5) + 0) % 3;
        const int a1 = ((colbase >> 5) + 1) % 3;
        const int F  = (colbase >> 4) & 1;
        #pragma unroll
        for (int m = 0; m < 4; ++m) {
            #pragma unroll
            for (int r = 0; r < 4; ++r) {
                int row = row0 + wm*64 + m*16 + lg*4 + r;
                const float* c3 = coords + (size_t)row * 3;
                float sn0, cs0, sn1, cs1;
                __sincosf(c3[a0] * freq, &sn0, &cs0);
                __sincosf(c3[a1] * freq, &sn1, &cs1);
                {
                    float A_ = F ? acc[m][1][r] : acc[m][0][r];
                    float B_ = F ? acc[m][0][r] : acc[m][1][r];
                    float x1 = (A_*cs0 - B_*sn0) * oscale, x2 = (A_*sn0 + B_*cs0) * oscale;
                    if (F) { acc[m][1][r] = x1; acc[m][0][r] = x2; }
                    else   { acc[m][0][r] = x1; acc[m][1][r] = x2; }
                }
                {
                    float A_ = F ? acc[m][3][r] : acc[m][2][r];
                    float B_ = F ? acc[m][2][r] : acc[m][3][r];
                    float x1 = (A_*cs1 - B_*sn1) * oscale, x2 = (A_*sn1 + B_*cs1) * oscale;
                    if (F) { acc[m][3][r] = x1; acc[m][2][r] = x2; }
                    else   { acc[m][2][r] = x1; acc[m][3][r] = x2; }
                }
            }
        }
        const int Lm1 = (1 << Lshift) - 1;
        int hh[4], tt[4];
        #pragma unroll
        for (int nt = 0; nt < 4; ++nt) {
            int j0 = colbase + nt*16;
            hh[nt] = j0 / HD;
            tt[nt] = j0 % HD + l15;
        }
        #pragma unroll
        for (int m = 0; m < 4; ++m)
            #pragma unroll
            for (int r = 0; r < 4; ++r) {
                int row = row0 + wm*64 + m*16 + lg*4 + r;
                int b = row >> Lshift, l = row & Lm1;
                #pragma unroll
                for (int nt = 0; nt < 4; ++nt)
                    out[(((size_t)b*NH + hh[nt]) << Lshift | l) * HD + tt[nt]] =
                        f2bf(acc[m][nt][r]);
            }
    } else {
        // V: re-transpose through first 32 KB of Sh -> bf16 (B,NH,96,LK)
        #pragma unroll
        for (int m = 0; m < 4; ++m)
            #pragma unroll
            for (int nt = 0; nt < 4; ++nt)
                #pragma unroll
                for (int r = 0; r < 4; ++r) {
                    int c  = wn*64 + nt*16 + l15;
                    int ri = wm*64 + m*16 + lg*4 + r;
                    *(ushort*)(base + c*256 + (((ri>>3) ^ (c&7))<<4) + (ri&7)*2)
                        = f2bf(acc[m][nt][r]);
                }
        __syncthreads();
        #pragma unroll
        for (int e = 0; e < 8; ++e) {
            int idx2 = tid + 256*e;
            int c = idx2 >> 4, r8 = idx2 & 15;
            uint4 val = *(const uint4*)(base + c*256 + ((r8 ^ (c&7))<<4));
            int j = col0 + c;
            int h = j / HD, t = j % HD;
            int row = row0 + r8*8;
            int b = row >> 12, l = row & (LK-1);
            *(uint4*)&out[(((size_t)b*NH + h)*HD + t)*LK + l] = val;
        }
    }
}

// Output projection GEMM: ctx bf16 -> out fp32, 128x128xBK64, XCD row-affinity.
__global__ __launch_bounds__(256)
void gemm_out(const ushort* __restrict__ X, const ushort* __restrict__ Wb,
              const float* __restrict__ bias, float* __restrict__ out)
{
    __shared__ ushort Sh[16384];
    char* As = (char*)Sh;
    char* Bs = (char*)Sh + 16384;

    const int tid  = threadIdx.x;
    const int w    = tid >> 6;
    const int lane = tid & 63;
    const int l15  = lane & 15;
    const int lg   = lane >> 4;
    const int wm   = w >> 1, wn = w & 1;

    const int L    = blockIdx.x;
    const int xcd  = L & 7;
    const int sq   = L >> 3;
    const int col0 = (sq % 6) * 128;
    const int row0 = (xcd * 4 + sq / 6) * 128;

    float4v acc[4][4];
    #pragma unroll
    for (int m = 0; m < 4; ++m)
        #pragma unroll
        for (int n = 0; n < 4; ++n) acc[m][n] = (float4v)0.f;

    int Pp[4], rrS[4], cbS[4];
    #pragma unroll
    for (int c = 0; c < 4; ++c) {
        int P = ((w*4 + c) << 10) + lane*16;
        int lgc = P ^ (((P >> 9) & 3) << 5);
        Pp[c]  = P;
        rrS[c] = lgc >> 7;
        cbS[c] = (lgc & 127) >> 1;
    }
    const ushort* xb = X  + (size_t)row0 * DM;
    const ushort* wb = Wb + (size_t)col0 * DM;

    int offA[2][4], offB[2][4];
    #pragma unroll
    for (int kk = 0; kk < 2; ++kk) {
        #pragma unroll
        for (int m = 0; m < 4; ++m) {
            int byte = (wm*64 + m*16 + l15)*128 + kk*64 + lg*16;
            offA[kk][m] = byte ^ (((byte >> 9) & 3) << 5);
            byte = (wn*64 + m*16 + l15)*128 + kk*64 + lg*16;
            offB[kk][m] = byte ^ (((byte >> 9) & 3) << 5);
        }
    }

    for (int kt = 0; kt < DM; kt += 64) {
        #pragma unroll
        for (int c = 0; c < 4; ++c) {
            gload_lds16(xb + (size_t)rrS[c]*DM + kt + cbS[c], As + Pp[c]);
            gload_lds16(wb + (size_t)rrS[c]*DM + kt + cbS[c], Bs + Pp[c]);
        }
        __syncthreads();
        #pragma unroll
        for (int kk = 0; kk < 2; ++kk) {
            short8v af[4], bfm[4];
            #pragma unroll
            for (int m = 0; m < 4; ++m)
                af[m] = *(const short8v*)(As + offA[kk][m]);
            #pragma unroll
            for (int n = 0; n < 4; ++n)
                bfm[n] = *(const short8v*)(Bs + offB[kk][n]);
            #pragma unroll
            for (int m = 0; m < 4; ++m)
                #pragma unroll
                for (int n = 0; n < 4; ++n)
                    acc[m][n] = __builtin_amdgcn_mfma_f32_16x16x32_bf16(af[m], bfm[n], acc[m][n], 0, 0, 0);
        }
        __syncthreads();
    }

    const int colbase = col0 + wn*64;
    float bvv[4];
    #pragma unroll
    for (int nt = 0; nt < 4; ++nt) bvv[nt] = bias[colbase + nt*16 + l15];
    #pragma unroll
    for (int m = 0; m < 4; ++m)
        #pragma unroll
        for (int r = 0; r < 4; ++r) {
            int row = row0 + wm*64 + m*16 + lg*4 + r;
            #pragma unroll
            for (int nt = 0; nt < 4; ++nt)
                out[(size_t)row*DM + colbase + nt*16 + l15] = acc[m][nt][r] + bvv[nt];
        }
}

// MFMA flash attention, KV-split 4, swapped-QK^T, exp2-domain softmax.
// Block = 4 waves x 128 q-rows (wave owns 32 = 2 fragments); KVBLK=64.
// XCD decode keeps each (bh,sc) K/V chunk L2-resident.
__global__ __launch_bounds__(256, 2)
void attn_mfma(const ushort* __restrict__ q, const ushort* __restrict__ k,
               const ushort* __restrict__ vt, ushort* __restrict__ opb,
               float* __restrict__ mlb)
{
    __shared__ ushort Ks[64*128];     // 16 KB, slot^=(row&7)
    __shared__ ushort Vs[96*64];      // 12 KB, slot^=(row&7)
    __shared__ ushort PsT[4][32][72]; // 18 KB: [wave][q][key]

    const int tid  = threadIdx.x;
    const int w    = tid >> 6;
    const int lane = tid & 63;
    const int l15  = lane & 15;
    const int lg   = lane >> 4;

    const int L   = blockIdx.x;
    const int xcd = L & 7;
    const int s   = L >> 3;                 // 0..127
    const int pr  = xcd*16 + (s >> 3);      // 0..127
    const int qt  = s & 7;                  // 0..7
    const int bh  = pr & 31;
    const int sc  = pr >> 5;                // 0..3

    const ushort* qg = q  + ((size_t)bh * LQ + qt*QB + w*32 + l15) * HD;
    const ushort* kg = k  + ((size_t)bh * LK + (size_t)sc * KC) * HD;
    const ushort* vg = vt + (size_t)bh * HD * LK + (size_t)sc * KC;

    short8v aq0[3], aq1[3];
    #pragma unroll
    for (int dc = 0; dc < 3; ++dc) {
        aq0[dc] = *(const short8v*)(qg + dc*32 + lg*8);
        aq1[dc] = *(const short8v*)(qg + 16*HD + dc*32 + lg*8);
    }

    int kdst[3], ksrc[3], vdst[3], vsrc[3];
    #pragma unroll
    for (int j = 0; j < 3; ++j) {
        int c = tid + 256*j;
        int kr = c / 12, ks = c % 12;
        kdst[j] = kr*256 + ((ks ^ (kr & 7)) << 4);
        ksrc[j] = kr*HD + ks*8;
        int vr = c >> 3, vs = c & 7;
        vdst[j] = vr*128 + ((vs ^ (vr & 7)) << 4);
        vsrc[j] = vr*LK + vs*8;
    }
    int tK[3], tV[2];
    #pragma unroll
    for (int dc = 0; dc < 3; ++dc) tK[dc] = ((dc*4 + lg) ^ (l15 & 7)) << 4;
    #pragma unroll
    for (int h2 = 0; h2 < 2; ++h2)  tV[h2] = ((h2*4 + lg) ^ (l15 & 7)) << 4;

    float4v o0[6], o1[6];
    #pragma unroll
    for (int dt = 0; dt < 6; ++dt) { o0[dt] = (float4v)0.f; o1[dt] = (float4v)0.f; }
    float m_0 = -1e30f, l_0 = 0.f;
    float m_1 = -1e30f, l_1 = 0.f;

    short8v kreg[3], vreg[3];
    #pragma unroll
    for (int j = 0; j < 3; ++j) {
        kreg[j] = *(const short8v*)(kg + ksrc[j]);
        vreg[j] = *(const short8v*)(vg + vsrc[j]);
    }
    #pragma unroll
    for (int j = 0; j < 3; ++j) {
        *(short8v*)((char*)Ks + kdst[j]) = kreg[j];
        *(short8v*)((char*)Vs + vdst[j]) = vreg[j];
    }
    __syncthreads();

    for (int t = 0; t < NT; ++t) {
        if (t + 1 < NT) {
            const ushort* kn = kg + (size_t)(t+1)*64*HD;
            const ushort* vn = vg + (t+1)*64;
            #pragma unroll
            for (int j = 0; j < 3; ++j) {
                kreg[j] = *(const short8v*)(kn + ksrc[j]);
                vreg[j] = *(const short8v*)(vn + vsrc[j]);
            }
        }

        // ---- S^T = K Q^T ----
        float4v s0[4], s1[4];
        __builtin_amdgcn_s_setprio(1);
        #pragma unroll
        for (int nt = 0; nt < 4; ++nt) {
            s0[nt] = (float4v)0.f;
            s1[nt] = (float4v)0.f;
            #pragma unroll
            for (int dc = 0; dc < 3; ++dc) {
                short8v bk = *(const short8v*)((const char*)Ks + nt*4096 + l15*256 + tK[dc]);
                s0[nt] = __builtin_amdgcn_mfma_f32_16x16x32_bf16(bk, aq0[dc], s0[nt], 0, 0, 0);
                s1[nt] = __builtin_amdgcn_mfma_f32_16x16x32_bf16(bk, aq1[dc], s1[nt], 0, 0, 0);
            }
        }
        __builtin_amdgcn_s_setprio(0);

        // ---- online softmax (log2 domain) ----
        float mt0 = -1e30f, mt1 = -1e30f;
        #pragma unroll
        for (int nt = 0; nt < 4; ++nt)
            #pragma unroll
            for (int r = 0; r < 4; ++r) {
                mt0 = fmaxf(mt0, s0[nt][r]);
                mt1 = fmaxf(mt1, s1[nt][r]);
            }
        mt0 = fmaxf(mt0, __shfl_xor(mt0, 16, 64));
        mt0 = fmaxf(mt0, __shfl_xor(mt0, 32, 64));
        mt1 = fmaxf(mt1, __shfl_xor(mt1, 16, 64));
        mt1 = fmaxf(mt1, __shfl_xor(mt1, 32, 64));

        if (__any((mt0 > m_0 + 11.5f) || (mt1 > m_1 + 11.5f))) {
            float mn0 = fmaxf(m_0, mt0), mn1 = fmaxf(m_1, mt1);
            float a0 = exp2hw(m_0 - mn0), a1 = exp2hw(m_1 - mn1);
            m_0 = mn0; m_1 = mn1;
            l_0 *= a0;  l_1 *= a1;
            float al0[4], al1[4];
            #pragma unroll
            for (int r = 0; r < 4; ++r) {
                al0[r] = __shfl(a0, lg*4 + r, 64);
                al1[r] = __shfl(a1, lg*4 + r, 64);
            }
            #pragma unroll
            for (int dt = 0; dt < 6; ++dt)
                #pragma unroll
                for (int r = 0; r < 4; ++r) {
                    o0[dt][r] *= al0[r];
                    o1[dt][r] *= al1[r];
                }
        }

        float ps0 = 0.f, ps1 = 0.f;
        #pragma unroll
        for (int nt = 0; nt < 4; ++nt)
            #pragma unroll
            for (int r = 0; r < 4; ++r) {
                float p0 = exp2hw(s0[nt][r] - m_0);
                float p1 = exp2hw(s1[nt][r] - m_1);
                s0[nt][r] = p0; ps0 += p0;
                s1[nt][r] = p1; ps1 += p1;
            }
        ps0 += __shfl_xor(ps0, 16, 64);
        ps0 += __shfl_xor(ps0, 32, 64);
        ps1 += __shfl_xor(ps1, 16, 64);
        ps1 += __shfl_xor(ps1, 32, 64);
        l_0 += ps0;
        l_1 += ps1;

        // ---- pack P^T rows ----
        #pragma unroll
        for (int nt = 0; nt < 4; ++nt) {
            uint2 pk0, pk1;
            pk0.x = cvtpk(s0[nt][0], s0[nt][1]);
            pk0.y = cvtpk(s0[nt][2], s0[nt][3]);
            pk1.x = cvtpk(s1[nt][0], s1[nt][1]);
            pk1.y = cvtpk(s1[nt][2], s1[nt][3]);
            *(uint2*)&PsT[w][l15][nt*16 + lg*4]      = pk0;
            *(uint2*)&PsT[w][16 + l15][nt*16 + lg*4] = pk1;
        }

        // ---- O += P V ----
        short8v a00 = *(const short8v*)&PsT[w][l15][lg*8];
        short8v a01 = *(const short8v*)&PsT[w][l15][32 + lg*8];
        short8v a10 = *(const short8v*)&PsT[w][16 + l15][lg*8];
        short8v a11 = *(const short8v*)&PsT[w][16 + l15][32 + lg*8];
        __builtin_amdgcn_s_setprio(1);
        #pragma unroll
        for (int dt = 0; dt < 6; ++dt) {
            short8v bv0 = *(const short8v*)((const char*)Vs + dt*2048 + l15*128 + tV[0]);
            short8v bv1 = *(const short8v*)((const char*)Vs + dt*2048 + l15*128 + tV[1]);
            o0[dt] = __builtin_amdgcn_mfma_f32_16x16x32_bf16(a00, bv0, o0[dt], 0, 0, 0);
            o0[dt] = __builtin_amdgcn_mfma_f32_16x16x32_bf16(a01, bv1, o0[dt], 0, 0, 0);
            o1[dt] = __builtin_amdgcn_mfma_f32_16x16x32_bf16(a10, bv0, o1[dt], 0, 0, 0);
            o1[dt] = __builtin_amdgcn_mfma_f32_16x16x32_bf16(a11, bv1, o1[dt], 0, 0, 0);
        }
        __builtin_amdgcn_s_setprio(0);
        __syncthreads();

        if (t + 1 < NT) {
            #pragma unroll
            for (int j = 0; j < 3; ++j) {
                *(short8v*)((char*)Ks + kdst[j]) = kreg[j];
                *(short8v*)((char*)Vs + vdst[j]) = vreg[j];
            }
        }
        __syncthreads();
    }

    // ---- epilogue: unnormalized bf16 partials ----
    ushort* ob = opb + (((size_t)sc * BH + bh) * LQ + qt*QB + w*32) * HD;
    #pragma unroll
    for (int r = 0; r < 4; ++r) {
        #pragma unroll
        for (int dt = 0; dt < 6; ++dt) {
            ob[(size_t)(lg*4 + r) * HD + dt*16 + l15]      = f2bf(o0[dt][r]);
            ob[(size_t)(16 + lg*4 + r) * HD + dt*16 + l15] = f2bf(o1[dt][r]);
        }
    }
    if (lane < 16) {
        size_t mlrow = ((size_t)sc * BH + bh) * LQ + qt*QB + w*32 + lane;
        mlb[mlrow*2 + 0] = m_0;
        mlb[mlrow*2 + 1] = l_0;
        mlb[(mlrow + 16)*2 + 0] = m_1;
        mlb[(mlrow + 16)*2 + 1] = l_1;
    }
}

// merge KVS=4 bf16 partials -> ctx bf16 (B, LQ, 768); m,l in log2 domain
__global__ __launch_bounds__(256)
void combine(const ushort* __restrict__ opb, const float* __restrict__ mlb,
             ushort* __restrict__ ctx)
{
    const int NROW = BH * LQ;
    int idx = blockIdx.x * 256 + threadIdx.x;
    int row = idx / 12, seg = idx % 12;

    float m[KVS], lv[KVS];
    #pragma unroll
    for (int i = 0; i < KVS; ++i) {
        m[i]  = mlb[((size_t)i*NROW + row)*2 + 0];
        lv[i] = mlb[((size_t)i*NROW + row)*2 + 1];
    }
    float ms = m[0];
    #pragma unroll
    for (int i = 1; i < KVS; ++i) ms = fmaxf(ms, m[i]);
    float wsum = 0.f, wgt[KVS];
    #pragma unroll
    for (int i = 0; i < KVS; ++i) {
        wgt[i] = exp2hw(m[i] - ms);
        wsum += lv[i] * wgt[i];
    }
    float inv = 1.f / wsum;

    float acc[8] = {};
    #pragma unroll
    for (int i = 0; i < KVS; ++i) {
        uint4 v = *(const uint4*)&opb[((size_t)i*NROW + row)*HD + seg*8];
        uint vv[4] = {v.x, v.y, v.z, v.w};
        #pragma unroll
        for (int j2 = 0; j2 < 4; ++j2) {
            acc[j2*2+0] += bf2f((ushort)(vv[j2] & 0xffff)) * wgt[i];
            acc[j2*2+1] += bf2f((ushort)(vv[j2] >> 16))    * wgt[i];
        }
    }

    int bh = row / LQ, l = row % LQ;
    int b = bh >> 3, h = bh & 7;
    ushort* o = ctx + ((size_t)b * LQ + l) * DM + h * HD + seg*8;
    uint4 pk;
    pk.x = cvtpk(acc[0]*inv, acc[1]*inv);
    pk.y = cvtpk(acc[2]*inv, acc[3]*inv);
    pk.z = cvtpk(acc[4]*inv, acc[5]*inv);
    pk.w = cvtpk(acc[6]*inv, acc[7]*inv);
    *(uint4*)o = pk;
}

extern "C" void kernel_launch(void* const* d_in, const int* in_sizes, int n_in,
                              void* d_out, int out_size, void* d_ws, size_t ws_size,
                              hipStream_t stream)
{
    const float* query = (const float*)d_in[0];
    const float* key   = (const float*)d_in[1];
    const float* value = (const float*)d_in[2];
    const float* cq    = (const float*)d_in[3];
    const float* ck    = (const float*)d_in[4];
    const float* Wq    = (const float*)d_in[5];
    const float* bqv   = (const float*)d_in[6];
    const float* Wk    = (const float*)d_in[7];
    const float* bkv   = (const float*)d_in[8];
    const float* Wv    = (const float*)d_in[9];
    const float* bvv   = (const float*)d_in[10];
    const float* Wo    = (const float*)d_in[11];
    const float* bov   = (const float*)d_in[12];
    float* out = (float*)d_out;

    const size_t NQ = (size_t)BQ * LQ * DM;   // 3,145,728
    const size_t NK = (size_t)BQ * LK * DM;   // 12,582,912
    const size_t NP = (size_t)KVS * BH * LQ * HD;  // 12,582,912 partial elems

    ushort* wq  = (ushort*)d_ws;        // 4 weight matrices contiguous
    ushort* wk  = wq  + NW;
    ushort* wv  = wk  + NW;
    ushort* wo  = wv  + NW;
    ushort* qws = wo  + NW;             // q bf16 (B,H,LQ,96)
    ushort* kws = qws + NQ;             // k bf16 (B,H,LK,96)
    ushort* vtb = kws + NK;             // v^T bf16 (B,H,96,LK)
    ushort* opb = vtb + NK;             // bf16 partials
    ushort* ctx = opb + NP;             // ctx bf16 (B,LQ,768)
    float*  mlb = (float*)(ctx + NQ);   // KVS*BH*LQ*(m,l)
    // total ~94 MB

    wcvt<<<4*(NW/1024), 256, 0, stream>>>(Wq, Wk, Wv, Wo, wq);
    qkv_gemm<<<1728, 256, 0, stream>>>(query, key, value, wq, wk, wv,
                                       bqv, bkv, bvv, cq, ck, qws, kws, vtb);
    attn_mfma<<<(LQ/QB) * BH * KVS, 256, 0, stream>>>(qws, kws, vtb, opb, mlb);
    combine<<<BH*LQ*12/256, 256, 0, stream>>>(opb, mlb, ctx);
    gemm_out<<<(BQ*LQ/128)*6, 256, 0, stream>>>(ctx, wo, bov, out);
}

// Round 14
// 172.012 us; speedup vs baseline: 1.0245x; 1.0245x over previous
//
#include <hip/hip_runtime.h>
#include <math.h>

#define DM 768
#define NH 8
#define HD 96
#define BQ 4
#define LQ 1024
#define LK 4096
#define BH (BQ*NH)
#define KVS 4              // kv-split factor
#define KC (LK/KVS)        // keys per chunk = 1024
#define NT (KC/64)         // 64-key tiles per block = 16
#define QB 128             // q-rows per block (32 per wave)
#define NW (DM*DM)

typedef unsigned short ushort;
typedef unsigned int uint;
typedef __attribute__((ext_vector_type(8))) short short8v;
typedef __attribute__((ext_vector_type(4))) float float4v;

// 1/sqrt(96) * log2(e)  (folded into Q projection)
#define QSCALE 0.14724444641f

static __device__ __forceinline__ ushort f2bf(float x) {
    union { float f; uint u; } c; c.f = x;
    uint u = c.u;
    u += ((u >> 16) & 1u) + 0x7fffu;   // RNE
    return (ushort)(u >> 16);
}

static __device__ __forceinline__ float bf2f(ushort x) {
    union { uint u; float f; } c; c.u = (uint)x << 16;
    return c.f;
}

static __device__ __forceinline__ uint cvtpk(float lo, float hi) {
    uint d;
    asm("v_cvt_pk_bf16_f32 %0, %1, %2" : "=v"(d) : "v"(lo), "v"(hi));
    return d;
}

static __device__ __forceinline__ float exp2hw(float x) {
#if __has_builtin(__builtin_amdgcn_exp2f)
    return __builtin_amdgcn_exp2f(x);
#else
    return __expf(x * 0.6931471805599453f);
#endif
}

static __device__ __forceinline__ void gload_lds16(const void* g, void* l) {
    __builtin_amdgcn_global_load_lds(
        (const __attribute__((address_space(1))) uint*)g,
        (__attribute__((address_space(3))) uint*)l, 16, 0, 0);
}

// weights fp32 -> bf16 (4 matrices into contiguous dst), 4 elems/thread
__global__ __launch_bounds__(256)
void wcvt(const float* __restrict__ w0, const float* __restrict__ w1,
          const float* __restrict__ w2, const float* __restrict__ w3,
          ushort* __restrict__ d)
{
    const int SEG = NW / 1024;           // 576 blocks per matrix
    int b = blockIdx.x;
    int wsel = b / SEG, ib = b % SEG;
    const float* s = (wsel == 0) ? w0 : (wsel == 1) ? w1 : (wsel == 2) ? w2 : w3;
    int i = ib * 256 + threadIdx.x;
    float4 v = ((const float4*)s)[i];
    uint2 o;
    o.x = (uint)f2bf(v.x) | ((uint)f2bf(v.y) << 16);
    o.y = (uint)f2bf(v.z) | ((uint)f2bf(v.w) << 16);
    ((uint2*)(d + (size_t)wsel * NW))[i] = o;
}

// Fused QKV projection GEMM, SMALL 64x128 tile for occupancy (4-5 blocks/CU).
// A (fp32 input) staged raw via gload_lds into [64][64] fp32 LDS (16 KB,
// 16-chunk XOR swizzle), converted bf16 on the LDS->reg read (R10 path).
// B (bf16 weights) gload_lds into [128][64] (16 KB). 32 KB total.
// Wave = 32x64 (acc 2x4 = 32 VGPR). Single-buffer 2-barrier loop.
// Segments: [0,384)=Q (RoPE), [384,1920)=K (RoPE), [1920,3456)=V (transpose).
__global__ __launch_bounds__(256, 4)
void qkv_gemm(const float* __restrict__ qf, const float* __restrict__ kf,
              const float* __restrict__ vf,
              const ushort* __restrict__ wqb, const ushort* __restrict__ wkb,
              const ushort* __restrict__ wvb,
              const float* __restrict__ bq, const float* __restrict__ bk,
              const float* __restrict__ bv,
              const float* __restrict__ cq, const float* __restrict__ ck,
              ushort* __restrict__ qws, ushort* __restrict__ kws,
              ushort* __restrict__ vtb)
{
    __shared__ ushort Sh[16384];         // 32 KB: As fp32 [0,16K), Bs bf16 [16K,32K)
    char* As = (char*)Sh;
    char* Bs = (char*)Sh + 16384;

    const int tid  = threadIdx.x;
    const int w    = tid >> 6;
    const int lane = tid & 63;
    const int l15  = lane & 15;
    const int lg   = lane >> 4;
    const int wm   = w >> 1, wn = w & 1;

    // segment decode (block-uniform)
    const int L = blockIdx.x;
    int seg, idx, Lshift, rpx;
    const float* X32; const ushort* Wbp; const float* bias; const float* coords;
    ushort* out; float oscale;
    if (L < 384)       { seg = 0; idx = L;        X32 = qf; Wbp = wqb; bias = bq; coords = cq; out = qws; Lshift = 10; rpx = 8;  oscale = QSCALE; }
    else if (L < 1920) { seg = 1; idx = L - 384;  X32 = kf; Wbp = wkb; bias = bk; coords = ck; out = kws; Lshift = 12; rpx = 32; oscale = 1.0f; }
    else               { seg = 2; idx = L - 1920; X32 = vf; Wbp = wvb; bias = bv; coords = 0;  out = vtb; Lshift = 12; rpx = 32; oscale = 1.0f; }

    const int xcd  = idx & 7;
    const int sq   = idx >> 3;
    const int col0 = (sq % 6) * 128;
    const int row0 = (xcd * rpx + sq / 6) * 64;

    float4v acc[2][4];
    #pragma unroll
    for (int m = 0; m < 2; ++m)
        #pragma unroll
        for (int n = 0; n < 4; ++n) acc[m][n] = (float4v)0.f;

    // ---- A staging geometry (fp32 [64][64], 16 chunks/row, j ^= r&15) ----
    int PA[4], rA[4], cA[4];
    #pragma unroll
    for (int c = 0; c < 4; ++c) {
        int P = ((w*4 + c) << 10) + lane*16;
        int r = P >> 8;                       // 0..63
        int j = ((P >> 4) & 15) ^ (r & 15);
        PA[c] = P;
        rA[c] = r;
        cA[c] = j * 4;                        // fp32 elem offset
    }
    // ---- B staging geometry (bf16 [128][64], 2-bit XOR swizzle) ----
    int PB[4], rB[4], cB[4];
    #pragma unroll
    for (int c = 0; c < 4; ++c) {
        int P = ((w*4 + c) << 10) + lane*16;
        int lgc = P ^ (((P >> 9) & 3) << 5);
        PB[c] = P;
        rB[c] = lgc >> 7;
        cB[c] = (lgc & 127) >> 1;
    }
    const float*  xb = X32 + (size_t)row0 * DM;
    const ushort* wb = Wbp + (size_t)col0 * DM;

    // ---- fragment read offsets ----
    int offA0[2][2], offA1[2][2], offB[2][4];
    #pragma unroll
    for (int kk = 0; kk < 2; ++kk) {
        #pragma unroll
        for (int m = 0; m < 2; ++m) {
            int R  = wm*32 + m*16 + l15;
            int j0 = kk*8 + lg*2;
            offA0[kk][m] = R*256 + (((j0    ) ^ (R & 15)) << 4);
            offA1[kk][m] = R*256 + (((j0 + 1) ^ (R & 15)) << 4);
        }
        #pragma unroll
        for (int n = 0; n < 4; ++n) {
            int byte = (wn*64 + n*16 + l15)*128 + kk*64 + lg*16;
            offB[kk][n] = byte ^ (((byte >> 9) & 3) << 5);
        }
    }

    for (int kt = 0; kt < DM; kt += 64) {
        #pragma unroll
        for (int c = 0; c < 4; ++c) {
            gload_lds16(xb + (size_t)rA[c]*DM + kt + cA[c], As + PA[c]);
            gload_lds16(wb + (size_t)rB[c]*DM + kt + cB[c], Bs + PB[c]);
        }
        __syncthreads();
        #pragma unroll
        for (int kk = 0; kk < 2; ++kk) {
            short8v af[2], bfm[4];
            #pragma unroll
            for (int m = 0; m < 2; ++m) {
                float4 x0 = *(const float4*)(As + offA0[kk][m]);
                float4 x1 = *(const float4*)(As + offA1[kk][m]);
                union { uint4 u; short8v s; } cv;
                cv.u.x = cvtpk(x0.x, x0.y);
                cv.u.y = cvtpk(x0.z, x0.w);
                cv.u.z = cvtpk(x1.x, x1.y);
                cv.u.w = cvtpk(x1.z, x1.w);
                af[m] = cv.s;
            }
            #pragma unroll
            for (int n = 0; n < 4; ++n)
                bfm[n] = *(const short8v*)(Bs + offB[kk][n]);
            #pragma unroll
            for (int m = 0; m < 2; ++m)
                #pragma unroll
                for (int n = 0; n < 4; ++n)
                    acc[m][n] = __builtin_amdgcn_mfma_f32_16x16x32_bf16(af[m], bfm[n], acc[m][n], 0, 0, 0);
        }
        __syncthreads();
    }

    const int colbase = col0 + wn*64;
    float bvv[4];
    #pragma unroll
    for (int nt = 0; nt < 4; ++nt) bvv[nt] = bias[colbase + nt*16 + l15];
    #pragma unroll
    for (int m = 0; m < 2; ++m)
        #pragma unroll
        for (int nt = 0; nt < 4; ++nt)
            #pragma unroll
            for (int r = 0; r < 4; ++r) acc[m][nt][r] += bvv[nt];

    if (seg < 2) {
        // RoPE + bf16 (B,NH,L,96) store
        const float freq = exp2f(-(float)l15 * 0.83048202372184058696f);
        const int a0 = ((colbase >> 5) + 0) % 3;
        const int a1 = ((colbase >> 5) + 1) % 3;
        const int F  = (colbase >> 4) & 1;
        #pragma unroll
        for (int m = 0; m < 2; ++m) {
            #pragma unroll
            for (int r = 0; r < 4; ++r) {
                int row = row0 + wm*32 + m*16 + lg*4 + r;
                const float* c3 = coords + (size_t)row * 3;
                float sn0, cs0, sn1, cs1;
                __sincosf(c3[a0] * freq, &sn0, &cs0);
                __sincosf(c3[a1] * freq, &sn1, &cs1);
                {
                    float A_ = F ? acc[m][1][r] : acc[m][0][r];
                    float B_ = F ? acc[m][0][r] : acc[m][1][r];
                    float x1 = (A_*cs0 - B_*sn0) * oscale, x2 = (A_*sn0 + B_*cs0) * oscale;
                    if (F) { acc[m][1][r] = x1; acc[m][0][r] = x2; }
                    else   { acc[m][0][r] = x1; acc[m][1][r] = x2; }
                }
                {
                    float A_ = F ? acc[m][3][r] : acc[m][2][r];
                    float B_ = F ? acc[m][2][r] : acc[m][3][r];
                    float x1 = (A_*cs1 - B_*sn1) * oscale, x2 = (A_*sn1 + B_*cs1) * oscale;
                    if (F) { acc[m][3][r] = x1; acc[m][2][r] = x2; }
                    else   { acc[m][2][r] = x1; acc[m][3][r] = x2; }
                }
            }
        }
        const int Lm1 = (1 << Lshift) - 1;
        int hh[4], tt[4];
        #pragma unroll
        for (int nt = 0; nt < 4; ++nt) {
            int j0 = colbase + nt*16;
            hh[nt] = j0 / HD;
            tt[nt] = j0 % HD + l15;
        }
        #pragma unroll
        for (int m = 0; m < 2; ++m)
            #pragma unroll
            for (int r = 0; r < 4; ++r) {
                int row = row0 + wm*32 + m*16 + lg*4 + r;
                int b = row >> Lshift, l = row & Lm1;
                #pragma unroll
                for (int nt = 0; nt < 4; ++nt)
                    out[(((size_t)b*NH + hh[nt]) << Lshift | l) * HD + tt[nt]] =
                        f2bf(acc[m][nt][r]);
            }
    } else {
        // V: re-transpose through Sh (16 KB needed) -> bf16 (B,NH,96,LK)
        // Cs[col 0..127][row 0..63]: addr = c*128 + (((ri>>3)^(c&7))<<4) + (ri&7)*2
        #pragma unroll
        for (int m = 0; m < 2; ++m)
            #pragma unroll
            for (int nt = 0; nt < 4; ++nt)
                #pragma unroll
                for (int r = 0; r < 4; ++r) {
                    int c  = wn*64 + nt*16 + l15;
                    int ri = wm*32 + m*16 + lg*4 + r;
                    *(ushort*)(As + c*128 + (((ri>>3) ^ (c&7))<<4) + (ri&7)*2)
                        = f2bf(acc[m][nt][r]);
                }
        __syncthreads();
        #pragma unroll
        for (int e = 0; e < 4; ++e) {
            int idx2 = tid + 256*e;          // 0..1023
            int c = idx2 >> 3, r8 = idx2 & 7;
            uint4 val = *(const uint4*)(As + c*128 + ((r8 ^ (c&7))<<4));
            int j = col0 + c;
            int h = j / HD, t = j % HD;
            int row = row0 + r8*8;
            int b = row >> 12, l = row & (LK-1);
            *(uint4*)&out[(((size_t)b*NH + h)*HD + t)*LK + l] = val;
        }
    }
}

// Output projection GEMM: ctx bf16 -> out fp32, 64x128 tile (24 KB LDS,
// grid 384 = 2x the old block count), XCD row-affinity.
__global__ __launch_bounds__(256, 4)
void gemm_out(const ushort* __restrict__ X, const ushort* __restrict__ Wb,
              const float* __restrict__ bias, float* __restrict__ out)
{
    __shared__ ushort Sh[12288];     // As bf16 [64][64] = 8 KB; Bs [128][64] = 16 KB
    char* As = (char*)Sh;
    char* Bs = (char*)Sh + 8192;

    const int tid  = threadIdx.x;
    const int w    = tid >> 6;
    const int lane = tid & 63;
    const int l15  = lane & 15;
    const int lg   = lane >> 4;
    const int wm   = w >> 1, wn = w & 1;

    const int L    = blockIdx.x;
    const int xcd  = L & 7;
    const int sq   = L >> 3;
    const int col0 = (sq % 6) * 128;
    const int row0 = (xcd * 8 + sq / 6) * 64;

    float4v acc[2][4];
    #pragma unroll
    for (int m = 0; m < 2; ++m)
        #pragma unroll
        for (int n = 0; n < 4; ++n) acc[m][n] = (float4v)0.f;

    // A staging (bf16 [64][64], 8 KB): 2 chunks/thread
    int PA[2], rA[2], cA[2];
    #pragma unroll
    for (int c = 0; c < 2; ++c) {
        int P = ((w*2 + c) << 10) + lane*16;
        int lgc = P ^ (((P >> 9) & 3) << 5);
        PA[c] = P;
        rA[c] = lgc >> 7;                    // 0..63
        cA[c] = (lgc & 127) >> 1;
    }
    // B staging (bf16 [128][64], 16 KB): 4 chunks/thread
    int PB[4], rB[4], cB[4];
    #pragma unroll
    for (int c = 0; c < 4; ++c) {
        int P = ((w*4 + c) << 10) + lane*16;
        int lgc = P ^ (((P >> 9) & 3) << 5);
        PB[c] = P;
        rB[c] = lgc >> 7;
        cB[c] = (lgc & 127) >> 1;
    }
    const ushort* xb = X  + (size_t)row0 * DM;
    const ushort* wb = Wb + (size_t)col0 * DM;

    int offA[2][2], offB[2][4];
    #pragma unroll
    for (int kk = 0; kk < 2; ++kk) {
        #pragma unroll
        for (int m = 0; m < 2; ++m) {
            int byte = (wm*32 + m*16 + l15)*128 + kk*64 + lg*16;
            offA[kk][m] = byte ^ (((byte >> 9) & 3) << 5);
        }
        #pragma unroll
        for (int n = 0; n < 4; ++n) {
            int byte = (wn*64 + n*16 + l15)*128 + kk*64 + lg*16;
            offB[kk][n] = byte ^ (((byte >> 9) & 3) << 5);
        }
    }

    for (int kt = 0; kt < DM; kt += 64) {
        #pragma unroll
        for (int c = 0; c < 2; ++c)
            gload_lds16(xb + (size_t)rA[c]*DM + kt + cA[c], As + PA[c]);
        #pragma unroll
        for (int c = 0; c < 4; ++c)
            gload_lds16(wb + (size_t)rB[c]*DM + kt + cB[c], Bs + PB[c]);
        __syncthreads();
        #pragma unroll
        for (int kk = 0; kk < 2; ++kk) {
            short8v af[2], bfm[4];
            #pragma unroll
            for (int m = 0; m < 2; ++m)
                af[m] = *(const short8v*)(As + offA[kk][m]);
            #pragma unroll
            for (int n = 0; n < 4; ++n)
                bfm[n] = *(const short8v*)(Bs + offB[kk][n]);
            #pragma unroll
            for (int m = 0; m < 2; ++m)
                #pragma unroll
                for (int n = 0; n < 4; ++n)
                    acc[m][n] = __builtin_amdgcn_mfma_f32_16x16x32_bf16(af[m], bfm[n], acc[m][n], 0, 0, 0);
        }
        __syncthreads();
    }

    const int colbase = col0 + wn*64;
    float bvv[4];
    #pragma unroll
    for (int nt = 0; nt < 4; ++nt) bvv[nt] = bias[colbase + nt*16 + l15];
    #pragma unroll
    for (int m = 0; m < 2; ++m)
        #pragma unroll
        for (int r = 0; r < 4; ++r) {
            int row = row0 + wm*32 + m*16 + lg*4 + r;
            #pragma unroll
            for (int nt = 0; nt < 4; ++nt)
                out[(size_t)row*DM + colbase + nt*16 + l15] = acc[m][nt][r] + bvv[nt];
        }
}

// MFMA flash attention, KV-split 4, swapped-QK^T, exp2-domain softmax.
// Block = 4 waves x 128 q-rows (wave owns 32 = 2 fragments); KVBLK=64.
// XCD decode keeps each (bh,sc) K/V chunk L2-resident. (Unchanged from R8.)
__global__ __launch_bounds__(256, 2)
void attn_mfma(const ushort* __restrict__ q, const ushort* __restrict__ k,
               const ushort* __restrict__ vt, ushort* __restrict__ opb,
               float* __restrict__ mlb)
{
    __shared__ ushort Ks[64*128];     // 16 KB, slot^=(row&7)
    __shared__ ushort Vs[96*64];      // 12 KB, slot^=(row&7)
    __shared__ ushort PsT[4][32][72]; // 18 KB: [wave][q][key]

    const int tid  = threadIdx.x;
    const int w    = tid >> 6;
    const int lane = tid & 63;
    const int l15  = lane & 15;
    const int lg   = lane >> 4;

    const int L   = blockIdx.x;
    const int xcd = L & 7;
    const int s   = L >> 3;                 // 0..127
    const int pr  = xcd*16 + (s >> 3);      // 0..127
    const int qt  = s & 7;                  // 0..7
    const int bh  = pr & 31;
    const int sc  = pr >> 5;                // 0..3

    const ushort* qg = q  + ((size_t)bh * LQ + qt*QB + w*32 + l15) * HD;
    const ushort* kg = k  + ((size_t)bh * LK + (size_t)sc * KC) * HD;
    const ushort* vg = vt + (size_t)bh * HD * LK + (size_t)sc * KC;

    short8v aq0[3], aq1[3];
    #pragma unroll
    for (int dc = 0; dc < 3; ++dc) {
        aq0[dc] = *(const short8v*)(qg + dc*32 + lg*8);
        aq1[dc] = *(const short8v*)(qg + 16*HD + dc*32 + lg*8);
    }

    int kdst[3], ksrc[3], vdst[3], vsrc[3];
    #pragma unroll
    for (int j = 0; j < 3; ++j) {
        int c = tid + 256*j;
        int kr = c / 12, ks = c % 12;
        kdst[j] = kr*256 + ((ks ^ (kr & 7)) << 4);
        ksrc[j] = kr*HD + ks*8;
        int vr = c >> 3, vs = c & 7;
        vdst[j] = vr*128 + ((vs ^ (vr & 7)) << 4);
        vsrc[j] = vr*LK + vs*8;
    }
    int tK[3], tV[2];
    #pragma unroll
    for (int dc = 0; dc < 3; ++dc) tK[dc] = ((dc*4 + lg) ^ (l15 & 7)) << 4;
    #pragma unroll
    for (int h2 = 0; h2 < 2; ++h2)  tV[h2] = ((h2*4 + lg) ^ (l15 & 7)) << 4;

    float4v o0[6], o1[6];
    #pragma unroll
    for (int dt = 0; dt < 6; ++dt) { o0[dt] = (float4v)0.f; o1[dt] = (float4v)0.f; }
    float m_0 = -1e30f, l_0 = 0.f;
    float m_1 = -1e30f, l_1 = 0.f;

    short8v kreg[3], vreg[3];
    #pragma unroll
    for (int j = 0; j < 3; ++j) {
        kreg[j] = *(const short8v*)(kg + ksrc[j]);
        vreg[j] = *(const short8v*)(vg + vsrc[j]);
    }
    #pragma unroll
    for (int j = 0; j < 3; ++j) {
        *(short8v*)((char*)Ks + kdst[j]) = kreg[j];
        *(short8v*)((char*)Vs + vdst[j]) = vreg[j];
    }
    __syncthreads();

    for (int t = 0; t < NT; ++t) {
        if (t + 1 < NT) {
            const ushort* kn = kg + (size_t)(t+1)*64*HD;
            const ushort* vn = vg + (t+1)*64;
            #pragma unroll
            for (int j = 0; j < 3; ++j) {
                kreg[j] = *(const short8v*)(kn + ksrc[j]);
                vreg[j] = *(const short8v*)(vn + vsrc[j]);
            }
        }

        // ---- S^T = K Q^T ----
        float4v s0[4], s1[4];
        __builtin_amdgcn_s_setprio(1);
        #pragma unroll
        for (int nt = 0; nt < 4; ++nt) {
            s0[nt] = (float4v)0.f;
            s1[nt] = (float4v)0.f;
            #pragma unroll
            for (int dc = 0; dc < 3; ++dc) {
                short8v bk = *(const short8v*)((const char*)Ks + nt*4096 + l15*256 + tK[dc]);
                s0[nt] = __builtin_amdgcn_mfma_f32_16x16x32_bf16(bk, aq0[dc], s0[nt], 0, 0, 0);
                s1[nt] = __builtin_amdgcn_mfma_f32_16x16x32_bf16(bk, aq1[dc], s1[nt], 0, 0, 0);
            }
        }
        __builtin_amdgcn_s_setprio(0);

        // ---- online softmax (log2 domain) ----
        float mt0 = -1e30f, mt1 = -1e30f;
        #pragma unroll
        for (int nt = 0; nt < 4; ++nt)
            #pragma unroll
            for (int r = 0; r < 4; ++r) {
                mt0 = fmaxf(mt0, s0[nt][r]);
                mt1 = fmaxf(mt1, s1[nt][r]);
            }
        mt0 = fmaxf(mt0, __shfl_xor(mt0, 16, 64));
        mt0 = fmaxf(mt0, __shfl_xor(mt0, 32, 64));
        mt1 = fmaxf(mt1, __shfl_xor(mt1, 16, 64));
        mt1 = fmaxf(mt1, __shfl_xor(mt1, 32, 64));

        if (__any((mt0 > m_0 + 11.5f) || (mt1 > m_1 + 11.5f))) {
            float mn0 = fmaxf(m_0, mt0), mn1 = fmaxf(m_1, mt1);
            float a0 = exp2hw(m_0 - mn0), a1 = exp2hw(m_1 - mn1);
            m_0 = mn0; m_1 = mn1;
            l_0 *= a0;  l_1 *= a1;
            float al0[4], al1[4];
            #pragma unroll
            for (int r = 0; r < 4; ++r) {
                al0[r] = __shfl(a0, lg*4 + r, 64);
                al1[r] = __shfl(a1, lg*4 + r, 64);
            }
            #pragma unroll
            for (int dt = 0; dt < 6; ++dt)
                #pragma unroll
                for (int r = 0; r < 4; ++r) {
                    o0[dt][r] *= al0[r];
                    o1[dt][r] *= al1[r];
                }
        }

        float ps0 = 0.f, ps1 = 0.f;
        #pragma unroll
        for (int nt = 0; nt < 4; ++nt)
            #pragma unroll
            for (int r = 0; r < 4; ++r) {
                float p0 = exp2hw(s0[nt][r] - m_0);
                float p1 = exp2hw(s1[nt][r] - m_1);
                s0[nt][r] = p0; ps0 += p0;
                s1[nt][r] = p1; ps1 += p1;
            }
        ps0 += __shfl_xor(ps0, 16, 64);
        ps0 += __shfl_xor(ps0, 32, 64);
        ps1 += __shfl_xor(ps1, 16, 64);
        ps1 += __shfl_xor(ps1, 32, 64);
        l_0 += ps0;
        l_1 += ps1;

        // ---- pack P^T rows ----
        #pragma unroll
        for (int nt = 0; nt < 4; ++nt) {
            uint2 pk0, pk1;
            pk0.x = cvtpk(s0[nt][0], s0[nt][1]);
            pk0.y = cvtpk(s0[nt][2], s0[nt][3]);
            pk1.x = cvtpk(s1[nt][0], s1[nt][1]);
            pk1.y = cvtpk(s1[nt][2], s1[nt][3]);
            *(uint2*)&PsT[w][l15][nt*16 + lg*4]      = pk0;
            *(uint2*)&PsT[w][16 + l15][nt*16 + lg*4] = pk1;
        }

        // ---- O += P V ----
        short8v a00 = *(const short8v*)&PsT[w][l15][lg*8];
        short8v a01 = *(const short8v*)&PsT[w][l15][32 + lg*8];
        short8v a10 = *(const short8v*)&PsT[w][16 + l15][lg*8];
        short8v a11 = *(const short8v*)&PsT[w][16 + l15][32 + lg*8];
        __builtin_amdgcn_s_setprio(1);
        #pragma unroll
        for (int dt = 0; dt < 6; ++dt) {
            short8v bv0 = *(const short8v*)((const char*)Vs + dt*2048 + l15*128 + tV[0]);
            short8v bv1 = *(const short8v*)((const char*)Vs + dt*2048 + l15*128 + tV[1]);
            o0[dt] = __builtin_amdgcn_mfma_f32_16x16x32_bf16(a00, bv0, o0[dt], 0, 0, 0);
            o0[dt] = __builtin_amdgcn_mfma_f32_16x16x32_bf16(a01, bv1, o0[dt], 0, 0, 0);
            o1[dt] = __builtin_amdgcn_mfma_f32_16x16x32_bf16(a10, bv0, o1[dt], 0, 0, 0);
            o1[dt] = __builtin_amdgcn_mfma_f32_16x16x32_bf16(a11, bv1, o1[dt], 0, 0, 0);
        }
        __builtin_amdgcn_s_setprio(0);
        __syncthreads();

        if (t + 1 < NT) {
            #pragma unroll
            for (int j = 0; j < 3; ++j) {
                *(short8v*)((char*)Ks + kdst[j]) = kreg[j];
                *(short8v*)((char*)Vs + vdst[j]) = vreg[j];
            }
        }
        __syncthreads();
    }

    // ---- epilogue: unnormalized bf16 partials ----
    ushort* ob = opb + (((size_t)sc * BH + bh) * LQ + qt*QB + w*32) * HD;
    #pragma unroll
    for (int r = 0; r < 4; ++r) {
        #pragma unroll
        for (int dt = 0; dt < 6; ++dt) {
            ob[(size_t)(lg*4 + r) * HD + dt*16 + l15]      = f2bf(o0[dt][r]);
            ob[(size_t)(16 + lg*4 + r) * HD + dt*16 + l15] = f2bf(o1[dt][r]);
        }
    }
    if (lane < 16) {
        size_t mlrow = ((size_t)sc * BH + bh) * LQ + qt*QB + w*32 + lane;
        mlb[mlrow*2 + 0] = m_0;
        mlb[mlrow*2 + 1] = l_0;
        mlb[(mlrow + 16)*2 + 0] = m_1;
        mlb[(mlrow + 16)*2 + 1] = l_1;
    }
}

// merge KVS=4 bf16 partials -> ctx bf16 (B, LQ, 768); m,l in log2 domain
__global__ __launch_bounds__(256)
void combine(const ushort* __restrict__ opb, const float* __restrict__ mlb,
             ushort* __restrict__ ctx)
{
    const int NROW = BH * LQ;
    int idx = blockIdx.x * 256 + threadIdx.x;
    int row = idx / 12, seg = idx % 12;

    float m[KVS], lv[KVS];
    #pragma unroll
    for (int i = 0; i < KVS; ++i) {
        m[i]  = mlb[((size_t)i*NROW + row)*2 + 0];
        lv[i] = mlb[((size_t)i*NROW + row)*2 + 1];
    }
    float ms = m[0];
    #pragma unroll
    for (int i = 1; i < KVS; ++i) ms = fmaxf(ms, m[i]);
    float wsum = 0.f, wgt[KVS];
    #pragma unroll
    for (int i = 0; i < KVS; ++i) {
        wgt[i] = exp2hw(m[i] - ms);
        wsum += lv[i] * wgt[i];
    }
    float inv = 1.f / wsum;

    float acc[8] = {};
    #pragma unroll
    for (int i = 0; i < KVS; ++i) {
        uint4 v = *(const uint4*)&opb[((size_t)i*NROW + row)*HD + seg*8];
        uint vv[4] = {v.x, v.y, v.z, v.w};
        #pragma unroll
        for (int j2 = 0; j2 < 4; ++j2) {
            acc[j2*2+0] += bf2f((ushort)(vv[j2] & 0xffff)) * wgt[i];
            acc[j2*2+1] += bf2f((ushort)(vv[j2] >> 16))    * wgt[i];
        }
    }

    int bh = row / LQ, l = row % LQ;
    int b = bh >> 3, h = bh & 7;
    ushort* o = ctx + ((size_t)b * LQ + l) * DM + h * HD + seg*8;
    uint4 pk;
    pk.x = cvtpk(acc[0]*inv, acc[1]*inv);
    pk.y = cvtpk(acc[2]*inv, acc[3]*inv);
    pk.z = cvtpk(acc[4]*inv, acc[5]*inv);
    pk.w = cvtpk(acc[6]*inv, acc[7]*inv);
    *(uint4*)o = pk;
}

extern "C" void kernel_launch(void* const* d_in, const int* in_sizes, int n_in,
                              void* d_out, int out_size, void* d_ws, size_t ws_size,
                              hipStream_t stream)
{
    const float* query = (const float*)d_in[0];
    const float* key   = (const float*)d_in[1];
    const float* value = (const float*)d_in[2];
    const float* cq    = (const float*)d_in[3];
    const float* ck    = (const float*)d_in[4];
    const float* Wq    = (const float*)d_in[5];
    const float* bqv   = (const float*)d_in[6];
    const float* Wk    = (const float*)d_in[7];
    const float* bkv   = (const float*)d_in[8];
    const float* Wv    = (const float*)d_in[9];
    const float* bvv   = (const float*)d_in[10];
    const float* Wo    = (const float*)d_in[11];
    const float* bov   = (const float*)d_in[12];
    float* out = (float*)d_out;

    const size_t NQ = (size_t)BQ * LQ * DM;   // 3,145,728
    const size_t NK = (size_t)BQ * LK * DM;   // 12,582,912
    const size_t NP = (size_t)KVS * BH * LQ * HD;  // 12,582,912 partial elems

    ushort* wq  = (ushort*)d_ws;        // 4 weight matrices contiguous
    ushort* wk  = wq  + NW;
    ushort* wv  = wk  + NW;
    ushort* wo  = wv  + NW;
    ushort* qws = wo  + NW;             // q bf16 (B,H,LQ,96)
    ushort* kws = qws + NQ;             // k bf16 (B,H,LK,96)
    ushort* vtb = kws + NK;             // v^T bf16 (B,H,96,LK)
    ushort* opb = vtb + NK;             // bf16 partials
    ushort* ctx = opb + NP;             // ctx bf16 (B,LQ,768)
    float*  mlb = (float*)(ctx + NQ);   // KVS*BH*LQ*(m,l)
    // total ~94 MB

    wcvt<<<4*(NW/1024), 256, 0, stream>>>(Wq, Wk, Wv, Wo, wq);
    qkv_gemm<<<3456, 256, 0, stream>>>(query, key, value, wq, wk, wv,
                                       bqv, bkv, bvv, cq, ck, qws, kws, vtb);
    attn_mfma<<<(LQ/QB) * BH * KVS, 256, 0, stream>>>(qws, kws, vtb, opb, mlb);
    combine<<<BH*LQ*12/256, 256, 0, stream>>>(opb, mlb, ctx);
    gemm_out<<<(BQ*LQ/64)*6, 256, 0, stream>>>(ctx, wo, bov, out);
}

// Round 15
// 171.735 us; speedup vs baseline: 1.0262x; 1.0016x over previous
//
#include <hip/hip_runtime.h>
#include <math.h>

#define DM 768
#define NH 8
#define HD 96
#define BQ 4
#define LQ 1024
#define LK 4096
#define BH (BQ*NH)
#define KVS 4              // kv-split factor
#define KC (LK/KVS)        // keys per chunk = 1024
#define NT (KC/64)         // 64-key tiles per block = 16
#define QB 128             // q-rows per block (32 per wave)
#define NW (DM*DM)
#define NKSTEP (DM/64)     // 12 K-steps

typedef unsigned short ushort;
typedef unsigned int uint;
typedef __attribute__((ext_vector_type(8))) short short8v;
typedef __attribute__((ext_vector_type(4))) float float4v;

// 1/sqrt(96) * log2(e)  (folded into Q projection)
#define QSCALE 0.14724444641f

static __device__ __forceinline__ ushort f2bf(float x) {
    union { float f; uint u; } c; c.f = x;
    uint u = c.u;
    u += ((u >> 16) & 1u) + 0x7fffu;   // RNE
    return (ushort)(u >> 16);
}

static __device__ __forceinline__ float bf2f(ushort x) {
    union { uint u; float f; } c; c.u = (uint)x << 16;
    return c.f;
}

static __device__ __forceinline__ uint cvtpk(float lo, float hi) {
    uint d;
    asm("v_cvt_pk_bf16_f32 %0, %1, %2" : "=v"(d) : "v"(lo), "v"(hi));
    return d;
}

static __device__ __forceinline__ float exp2hw(float x) {
#if __has_builtin(__builtin_amdgcn_exp2f)
    return __builtin_amdgcn_exp2f(x);
#else
    return __expf(x * 0.6931471805599453f);
#endif
}

static __device__ __forceinline__ void gload_lds16(const void* g, void* l) {
    __builtin_amdgcn_global_load_lds(
        (const __attribute__((address_space(1))) uint*)g,
        (__attribute__((address_space(3))) uint*)l, 16, 0, 0);
}

// weights fp32 -> bf16 (4 matrices into contiguous dst), 4 elems/thread
__global__ __launch_bounds__(256)
void wcvt(const float* __restrict__ w0, const float* __restrict__ w1,
          const float* __restrict__ w2, const float* __restrict__ w3,
          ushort* __restrict__ d)
{
    const int SEG = NW / 1024;           // 576 blocks per matrix
    int b = blockIdx.x;
    int wsel = b / SEG, ib = b % SEG;
    const float* s = (wsel == 0) ? w0 : (wsel == 1) ? w1 : (wsel == 2) ? w2 : w3;
    int i = ib * 256 + threadIdx.x;
    float4 v = ((const float4*)s)[i];
    uint2 o;
    o.x = (uint)f2bf(v.x) | ((uint)f2bf(v.y) << 16);
    o.y = (uint)f2bf(v.z) | ((uint)f2bf(v.w) << 16);
    ((uint2*)(d + (size_t)wsel * NW))[i] = o;
}

// Fused QKV projection GEMM, 128x256 tile (best staging intensity, R12) with
// attn-style reg-staged prefetch: loads for tile t+1 issued BEFORE compute(t)
// (register loads cross the barrier un-drained in effect: their wait lands at
// the post-barrier ds_write, after compute covered the L2 latency). Single-
// buffered 48 KB LDS, 2 barriers/K-step. Segments: [0,96)=Q, [96,480)=K,
// [480,864)=V (transpose). XCD row-affinity per segment.
__global__ __launch_bounds__(256, 2)
void qkv_gemm(const float* __restrict__ qf, const float* __restrict__ kf,
              const float* __restrict__ vf,
              const ushort* __restrict__ wqb, const ushort* __restrict__ wkb,
              const ushort* __restrict__ wvb,
              const float* __restrict__ bq, const float* __restrict__ bk,
              const float* __restrict__ bv,
              const float* __restrict__ cq, const float* __restrict__ ck,
              ushort* __restrict__ qws, ushort* __restrict__ kws,
              ushort* __restrict__ vtb)
{
    // 48 KB: As bf16 [128][64] = [0,16K); Bs bf16 [256][64] = [16K,48K)
    __shared__ ushort Sh[24576];
    char* As = (char*)Sh;
    char* Bs = (char*)Sh + 16384;

    const int tid  = threadIdx.x;
    const int w    = tid >> 6;
    const int lane = tid & 63;
    const int l15  = lane & 15;
    const int lg   = lane >> 4;
    const int wm   = w >> 1, wn = w & 1;

    // segment decode (block-uniform)
    const int L = blockIdx.x;
    int seg, idx, Lshift, rpx;
    const float* X32; const ushort* Wbp; const float* bias; const float* coords;
    ushort* out; float oscale;
    if (L < 96)       { seg = 0; idx = L;       X32 = qf; Wbp = wqb; bias = bq; coords = cq; out = qws; Lshift = 10; rpx = 4;  oscale = QSCALE; }
    else if (L < 480) { seg = 1; idx = L - 96;  X32 = kf; Wbp = wkb; bias = bk; coords = ck; out = kws; Lshift = 12; rpx = 16; oscale = 1.0f; }
    else              { seg = 2; idx = L - 480; X32 = vf; Wbp = wvb; bias = bv; coords = 0;  out = vtb; Lshift = 12; rpx = 16; oscale = 1.0f; }

    const int xcd  = idx & 7;
    const int sq   = idx >> 3;
    const int col0 = (sq % 3) * 256;
    const int row0 = (xcd * rpx + sq / 3) * 128;

    float4v acc[4][8];
    #pragma unroll
    for (int m = 0; m < 4; ++m)
        #pragma unroll
        for (int n = 0; n < 8; ++n) acc[m][n] = (float4v)0.f;

    // A staging geometry (4 chunks, 16 KB bf16, 2-bit XOR swizzle)
    int PA[4], rA[4], cA[4];
    #pragma unroll
    for (int c = 0; c < 4; ++c) {
        int P = ((w*4 + c) << 10) + lane*16;
        int lgc = P ^ (((P >> 9) & 3) << 5);
        PA[c] = P;
        rA[c] = lgc >> 7;
        cA[c] = (lgc & 127) >> 1;
    }
    // B staging geometry (8 chunks, 32 KB bf16, same per-row swizzle)
    int PB[8], rB[8], cB[8];
    #pragma unroll
    for (int c = 0; c < 8; ++c) {
        int P = ((w*8 + c) << 10) + lane*16;
        int lgc = P ^ (((P >> 9) & 3) << 5);
        PB[c] = P;
        rB[c] = lgc >> 7;
        cB[c] = (lgc & 127) >> 1;
    }
    const float*  xb = X32 + (size_t)row0 * DM;
    const ushort* wb = Wbp + (size_t)col0 * DM;

    // fragment read offsets
    int offA[2][4], offB[2][8];
    #pragma unroll
    for (int kk = 0; kk < 2; ++kk) {
        #pragma unroll
        for (int m = 0; m < 4; ++m) {
            int byte = (wm*64 + m*16 + l15)*128 + kk*64 + lg*16;
            offA[kk][m] = byte ^ (((byte >> 9) & 3) << 5);
        }
        #pragma unroll
        for (int n = 0; n < 8; ++n) {
            int byte = (wn*128 + n*16 + l15)*128 + kk*64 + lg*16;
            offB[kk][n] = byte ^ (((byte >> 9) & 3) << 5);
        }
    }

    // ---- prologue: tile 0 -> regs -> LDS ----
    float4 fa[4], fb[4];
    short8v bregs[8];
    #pragma unroll
    for (int c = 0; c < 4; ++c) {
        const float* src = xb + (size_t)rA[c]*DM + cA[c];
        fa[c] = *(const float4*)src;
        fb[c] = *(const float4*)(src + 4);
    }
    #pragma unroll
    for (int c = 0; c < 8; ++c)
        bregs[c] = *(const short8v*)(wb + (size_t)rB[c]*DM + cB[c]);
    #pragma unroll
    for (int c = 0; c < 4; ++c) {
        uint4 pk;
        pk.x = cvtpk(fa[c].x, fa[c].y);
        pk.y = cvtpk(fa[c].z, fa[c].w);
        pk.z = cvtpk(fb[c].x, fb[c].y);
        pk.w = cvtpk(fb[c].z, fb[c].w);
        *(uint4*)(As + PA[c]) = pk;
    }
    #pragma unroll
    for (int c = 0; c < 8; ++c)
        *(short8v*)(Bs + PB[c]) = bregs[c];
    __syncthreads();

    for (int t = 0; t < NKSTEP; ++t) {
        // prefetch tile t+1 into regs (latency hides under compute below)
        if (t + 1 < NKSTEP) {
            const int kn = (t + 1) * 64;
            #pragma unroll
            for (int c = 0; c < 4; ++c) {
                const float* src = xb + (size_t)rA[c]*DM + kn + cA[c];
                fa[c] = *(const float4*)src;
                fb[c] = *(const float4*)(src + 4);
            }
            #pragma unroll
            for (int c = 0; c < 8; ++c)
                bregs[c] = *(const short8v*)(wb + (size_t)rB[c]*DM + kn + cB[c]);
        }
        // compute tile t
        #pragma unroll
        for (int kk = 0; kk < 2; ++kk) {
            short8v af[4], bfm[8];
            #pragma unroll
            for (int m = 0; m < 4; ++m)
                af[m] = *(const short8v*)(As + offA[kk][m]);
            #pragma unroll
            for (int n = 0; n < 8; ++n)
                bfm[n] = *(const short8v*)(Bs + offB[kk][n]);
            #pragma unroll
            for (int m = 0; m < 4; ++m)
                #pragma unroll
                for (int n = 0; n < 8; ++n)
                    acc[m][n] = __builtin_amdgcn_mfma_f32_16x16x32_bf16(af[m], bfm[n], acc[m][n], 0, 0, 0);
        }
        __syncthreads();   // all waves done reading tile t
        if (t + 1 < NKSTEP) {
            #pragma unroll
            for (int c = 0; c < 4; ++c) {
                uint4 pk;
                pk.x = cvtpk(fa[c].x, fa[c].y);
                pk.y = cvtpk(fa[c].z, fa[c].w);
                pk.z = cvtpk(fb[c].x, fb[c].y);
                pk.w = cvtpk(fb[c].z, fb[c].w);
                *(uint4*)(As + PA[c]) = pk;
            }
            #pragma unroll
            for (int c = 0; c < 8; ++c)
                *(short8v*)(Bs + PB[c]) = bregs[c];
        }
        __syncthreads();   // tile t+1 visible
    }

    const int colbase = col0 + wn*128;   // 128-aligned -> RoPE F=0 always
    float bvv[8];
    #pragma unroll
    for (int nt = 0; nt < 8; ++nt) bvv[nt] = bias[colbase + nt*16 + l15];
    #pragma unroll
    for (int m = 0; m < 4; ++m)
        #pragma unroll
        for (int nt = 0; nt < 8; ++nt)
            #pragma unroll
            for (int r = 0; r < 4; ++r) acc[m][nt][r] += bvv[nt];

    if (seg < 2) {
        // RoPE: pair p = frags (2p, 2p+1); axis per 32-col chunk
        const float freq = exp2f(-(float)l15 * 0.83048202372184058696f);
        int ap[4];
        #pragma unroll
        for (int p = 0; p < 4; ++p) ap[p] = ((colbase >> 5) + p) % 3;
        #pragma unroll
        for (int m = 0; m < 4; ++m) {
            #pragma unroll
            for (int r = 0; r < 4; ++r) {
                int row = row0 + wm*64 + m*16 + lg*4 + r;
                const float* c3 = coords + (size_t)row * 3;
                #pragma unroll
                for (int p = 0; p < 4; ++p) {
                    float sn, cs;
                    __sincosf(c3[ap[p]] * freq, &sn, &cs);
                    float A_ = acc[m][2*p][r], B_ = acc[m][2*p+1][r];
                    acc[m][2*p][r]   = (A_*cs - B_*sn) * oscale;
                    acc[m][2*p+1][r] = (A_*sn + B_*cs) * oscale;
                }
            }
        }
        const int Lm1 = (1 << Lshift) - 1;
        int hh[8], tt[8];
        #pragma unroll
        for (int nt = 0; nt < 8; ++nt) {
            int j0 = colbase + nt*16;
            hh[nt] = j0 / HD;
            tt[nt] = j0 % HD + l15;
        }
        #pragma unroll
        for (int m = 0; m < 4; ++m)
            #pragma unroll
            for (int r = 0; r < 4; ++r) {
                int row = row0 + wm*64 + m*16 + lg*4 + r;
                int b = row >> Lshift, l = row & Lm1;
                #pragma unroll
                for (int nt = 0; nt < 8; ++nt)
                    out[(((size_t)b*NH + hh[nt]) << Lshift | l) * HD + tt[nt]] =
                        f2bf(acc[m][nt][r]);
            }
    } else {
        // V: re-transpose in two 128-col halves through first 32 KB of Sh
        #pragma unroll
        for (int h2 = 0; h2 < 2; ++h2) {
            __syncthreads();
            if (wn == h2) {
                #pragma unroll
                for (int m = 0; m < 4; ++m)
                    #pragma unroll
                    for (int nt = 0; nt < 8; ++nt)
                        #pragma unroll
                        for (int r = 0; r < 4; ++r) {
                            int c  = nt*16 + l15;                 // 0..127 within half
                            int ri = wm*64 + m*16 + lg*4 + r;     // 0..127
                            *(ushort*)((char*)Sh + c*256 + (((ri>>3) ^ (c&7))<<4) + (ri&7)*2)
                                = f2bf(acc[m][nt][r]);
                        }
            }
            __syncthreads();
            #pragma unroll
            for (int e = 0; e < 8; ++e) {
                int idx2 = tid + 256*e;
                int c = idx2 >> 4, r8 = idx2 & 15;
                uint4 val = *(const uint4*)((const char*)Sh + c*256 + ((r8 ^ (c&7))<<4));
                int j = col0 + h2*128 + c;
                int h = j / HD, t = j % HD;
                int row = row0 + r8*8;
                int b = row >> 12, l = row & (LK-1);
                *(uint4*)&out[(((size_t)b*NH + h)*HD + t)*LK + l] = val;
            }
        }
    }
}

// Output projection GEMM: ctx bf16 -> out fp32, 64x128 tile (24 KB LDS,
// grid 384 = 4 blocks/CU), XCD row-affinity. (R14's proven fast form.)
__global__ __launch_bounds__(256, 4)
void gemm_out(const ushort* __restrict__ X, const ushort* __restrict__ Wb,
              const float* __restrict__ bias, float* __restrict__ out)
{
    __shared__ ushort Sh[12288];     // As bf16 [64][64] = 8 KB; Bs [128][64] = 16 KB
    char* As = (char*)Sh;
    char* Bs = (char*)Sh + 8192;

    const int tid  = threadIdx.x;
    const int w    = tid >> 6;
    const int lane = tid & 63;
    const int l15  = lane & 15;
    const int lg   = lane >> 4;
    const int wm   = w >> 1, wn = w & 1;

    const int L    = blockIdx.x;
    const int xcd  = L & 7;
    const int sq   = L >> 3;
    const int col0 = (sq % 6) * 128;
    const int row0 = (xcd * 8 + sq / 6) * 64;

    float4v acc[2][4];
    #pragma unroll
    for (int m = 0; m < 2; ++m)
        #pragma unroll
        for (int n = 0; n < 4; ++n) acc[m][n] = (float4v)0.f;

    int PA[2], rA[2], cA[2];
    #pragma unroll
    for (int c = 0; c < 2; ++c) {
        int P = ((w*2 + c) << 10) + lane*16;
        int lgc = P ^ (((P >> 9) & 3) << 5);
        PA[c] = P;
        rA[c] = lgc >> 7;
        cA[c] = (lgc & 127) >> 1;
    }
    int PB[4], rB[4], cB[4];
    #pragma unroll
    for (int c = 0; c < 4; ++c) {
        int P = ((w*4 + c) << 10) + lane*16;
        int lgc = P ^ (((P >> 9) & 3) << 5);
        PB[c] = P;
        rB[c] = lgc >> 7;
        cB[c] = (lgc & 127) >> 1;
    }
    const ushort* xb = X  + (size_t)row0 * DM;
    const ushort* wb = Wb + (size_t)col0 * DM;

    int offA[2][2], offB[2][4];
    #pragma unroll
    for (int kk = 0; kk < 2; ++kk) {
        #pragma unroll
        for (int m = 0; m < 2; ++m) {
            int byte = (wm*32 + m*16 + l15)*128 + kk*64 + lg*16;
            offA[kk][m] = byte ^ (((byte >> 9) & 3) << 5);
        }
        #pragma unroll
        for (int n = 0; n < 4; ++n) {
            int byte = (wn*64 + n*16 + l15)*128 + kk*64 + lg*16;
            offB[kk][n] = byte ^ (((byte >> 9) & 3) << 5);
        }
    }

    for (int kt = 0; kt < DM; kt += 64) {
        #pragma unroll
        for (int c = 0; c < 2; ++c)
            gload_lds16(xb + (size_t)rA[c]*DM + kt + cA[c], As + PA[c]);
        #pragma unroll
        for (int c = 0; c < 4; ++c)
            gload_lds16(wb + (size_t)rB[c]*DM + kt + cB[c], Bs + PB[c]);
        __syncthreads();
        #pragma unroll
        for (int kk = 0; kk < 2; ++kk) {
            short8v af[2], bfm[4];
            #pragma unroll
            for (int m = 0; m < 2; ++m)
                af[m] = *(const short8v*)(As + offA[kk][m]);
            #pragma unroll
            for (int n = 0; n < 4; ++n)
                bfm[n] = *(const short8v*)(Bs + offB[kk][n]);
            #pragma unroll
            for (int m = 0; m < 2; ++m)
                #pragma unroll
                for (int n = 0; n < 4; ++n)
                    acc[m][n] = __builtin_amdgcn_mfma_f32_16x16x32_bf16(af[m], bfm[n], acc[m][n], 0, 0, 0);
        }
        __syncthreads();
    }

    const int colbase = col0 + wn*64;
    float bvv[4];
    #pragma unroll
    for (int nt = 0; nt < 4; ++nt) bvv[nt] = bias[colbase + nt*16 + l15];
    #pragma unroll
    for (int m = 0; m < 2; ++m)
        #pragma unroll
        for (int r = 0; r < 4; ++r) {
            int row = row0 + wm*32 + m*16 + lg*4 + r;
            #pragma unroll
            for (int nt = 0; nt < 4; ++nt)
                out[(size_t)row*DM + colbase + nt*16 + l15] = acc[m][nt][r] + bvv[nt];
        }
}

// MFMA flash attention, KV-split 4, swapped-QK^T, exp2-domain softmax.
// Block = 4 waves x 128 q-rows (wave owns 32 = 2 fragments); KVBLK=64.
// XCD decode keeps each (bh,sc) K/V chunk L2-resident. (Unchanged.)
__global__ __launch_bounds__(256, 2)
void attn_mfma(const ushort* __restrict__ q, const ushort* __restrict__ k,
               const ushort* __restrict__ vt, ushort* __restrict__ opb,
               float* __restrict__ mlb)
{
    __shared__ ushort Ks[64*128];     // 16 KB, slot^=(row&7)
    __shared__ ushort Vs[96*64];      // 12 KB, slot^=(row&7)
    __shared__ ushort PsT[4][32][72]; // 18 KB: [wave][q][key]

    const int tid  = threadIdx.x;
    const int w    = tid >> 6;
    const int lane = tid & 63;
    const int l15  = lane & 15;
    const int lg   = lane >> 4;

    const int L   = blockIdx.x;
    const int xcd = L & 7;
    const int s   = L >> 3;                 // 0..127
    const int pr  = xcd*16 + (s >> 3);      // 0..127
    const int qt  = s & 7;                  // 0..7
    const int bh  = pr & 31;
    const int sc  = pr >> 5;                // 0..3

    const ushort* qg = q  + ((size_t)bh * LQ + qt*QB + w*32 + l15) * HD;
    const ushort* kg = k  + ((size_t)bh * LK + (size_t)sc * KC) * HD;
    const ushort* vg = vt + (size_t)bh * HD * LK + (size_t)sc * KC;

    short8v aq0[3], aq1[3];
    #pragma unroll
    for (int dc = 0; dc < 3; ++dc) {
        aq0[dc] = *(const short8v*)(qg + dc*32 + lg*8);
        aq1[dc] = *(const short8v*)(qg + 16*HD + dc*32 + lg*8);
    }

    int kdst[3], ksrc[3], vdst[3], vsrc[3];
    #pragma unroll
    for (int j = 0; j < 3; ++j) {
        int c = tid + 256*j;
        int kr = c / 12, ks = c % 12;
        kdst[j] = kr*256 + ((ks ^ (kr & 7)) << 4);
        ksrc[j] = kr*HD + ks*8;
        int vr = c >> 3, vs = c & 7;
        vdst[j] = vr*128 + ((vs ^ (vr & 7)) << 4);
        vsrc[j] = vr*LK + vs*8;
    }
    int tK[3], tV[2];
    #pragma unroll
    for (int dc = 0; dc < 3; ++dc) tK[dc] = ((dc*4 + lg) ^ (l15 & 7)) << 4;
    #pragma unroll
    for (int h2 = 0; h2 < 2; ++h2)  tV[h2] = ((h2*4 + lg) ^ (l15 & 7)) << 4;

    float4v o0[6], o1[6];
    #pragma unroll
    for (int dt = 0; dt < 6; ++dt) { o0[dt] = (float4v)0.f; o1[dt] = (float4v)0.f; }
    float m_0 = -1e30f, l_0 = 0.f;
    float m_1 = -1e30f, l_1 = 0.f;

    short8v kreg[3], vreg[3];
    #pragma unroll
    for (int j = 0; j < 3; ++j) {
        kreg[j] = *(const short8v*)(kg + ksrc[j]);
        vreg[j] = *(const short8v*)(vg + vsrc[j]);
    }
    #pragma unroll
    for (int j = 0; j < 3; ++j) {
        *(short8v*)((char*)Ks + kdst[j]) = kreg[j];
        *(short8v*)((char*)Vs + vdst[j]) = vreg[j];
    }
    __syncthreads();

    for (int t = 0; t < NT; ++t) {
        if (t + 1 < NT) {
            const ushort* kn = kg + (size_t)(t+1)*64*HD;
            const ushort* vn = vg + (t+1)*64;
            #pragma unroll
            for (int j = 0; j < 3; ++j) {
                kreg[j] = *(const short8v*)(kn + ksrc[j]);
                vreg[j] = *(const short8v*)(vn + vsrc[j]);
            }
        }

        // ---- S^T = K Q^T ----
        float4v s0[4], s1[4];
        __builtin_amdgcn_s_setprio(1);
        #pragma unroll
        for (int nt = 0; nt < 4; ++nt) {
            s0[nt] = (float4v)0.f;
            s1[nt] = (float4v)0.f;
            #pragma unroll
            for (int dc = 0; dc < 3; ++dc) {
                short8v bk = *(const short8v*)((const char*)Ks + nt*4096 + l15*256 + tK[dc]);
                s0[nt] = __builtin_amdgcn_mfma_f32_16x16x32_bf16(bk, aq0[dc], s0[nt], 0, 0, 0);
                s1[nt] = __builtin_amdgcn_mfma_f32_16x16x32_bf16(bk, aq1[dc], s1[nt], 0, 0, 0);
            }
        }
        __builtin_amdgcn_s_setprio(0);

        // ---- online softmax (log2 domain) ----
        float mt0 = -1e30f, mt1 = -1e30f;
        #pragma unroll
        for (int nt = 0; nt < 4; ++nt)
            #pragma unroll
            for (int r = 0; r < 4; ++r) {
                mt0 = fmaxf(mt0, s0[nt][r]);
                mt1 = fmaxf(mt1, s1[nt][r]);
            }
        mt0 = fmaxf(mt0, __shfl_xor(mt0, 16, 64));
        mt0 = fmaxf(mt0, __shfl_xor(mt0, 32, 64));
        mt1 = fmaxf(mt1, __shfl_xor(mt1, 16, 64));
        mt1 = fmaxf(mt1, __shfl_xor(mt1, 32, 64));

        if (__any((mt0 > m_0 + 11.5f) || (mt1 > m_1 + 11.5f))) {
            float mn0 = fmaxf(m_0, mt0), mn1 = fmaxf(m_1, mt1);
            float a0 = exp2hw(m_0 - mn0), a1 = exp2hw(m_1 - mn1);
            m_0 = mn0; m_1 = mn1;
            l_0 *= a0;  l_1 *= a1;
            float al0[4], al1[4];
            #pragma unroll
            for (int r = 0; r < 4; ++r) {
                al0[r] = __shfl(a0, lg*4 + r, 64);
                al1[r] = __shfl(a1, lg*4 + r, 64);
            }
            #pragma unroll
            for (int dt = 0; dt < 6; ++dt)
                #pragma unroll
                for (int r = 0; r < 4; ++r) {
                    o0[dt][r] *= al0[r];
                    o1[dt][r] *= al1[r];
                }
        }

        float ps0 = 0.f, ps1 = 0.f;
        #pragma unroll
        for (int nt = 0; nt < 4; ++nt)
            #pragma unroll
            for (int r = 0; r < 4; ++r) {
                float p0 = exp2hw(s0[nt][r] - m_0);
                float p1 = exp2hw(s1[nt][r] - m_1);
                s0[nt][r] = p0; ps0 += p0;
                s1[nt][r] = p1; ps1 += p1;
            }
        ps0 += __shfl_xor(ps0, 16, 64);
        ps0 += __shfl_xor(ps0, 32, 64);
        ps1 += __shfl_xor(ps1, 16, 64);
        ps1 += __shfl_xor(ps1, 32, 64);
        l_0 += ps0;
        l_1 += ps1;

        // ---- pack P^T rows ----
        #pragma unroll
        for (int nt = 0; nt < 4; ++nt) {
            uint2 pk0, pk1;
            pk0.x = cvtpk(s0[nt][0], s0[nt][1]);
            pk0.y = cvtpk(s0[nt][2], s0[nt][3]);
            pk1.x = cvtpk(s1[nt][0], s1[nt][1]);
            pk1.y = cvtpk(s1[nt][2], s1[nt][3]);
            *(uint2*)&PsT[w][l15][nt*16 + lg*4]      = pk0;
            *(uint2*)&PsT[w][16 + l15][nt*16 + lg*4] = pk1;
        }

        // ---- O += P V ----
        short8v a00 = *(const short8v*)&PsT[w][l15][lg*8];
        short8v a01 = *(const short8v*)&PsT[w][l15][32 + lg*8];
        short8v a10 = *(const short8v*)&PsT[w][16 + l15][lg*8];
        short8v a11 = *(const short8v*)&PsT[w][16 + l15][32 + lg*8];
        __builtin_amdgcn_s_setprio(1);
        #pragma unroll
        for (int dt = 0; dt < 6; ++dt) {
            short8v bv0 = *(const short8v*)((const char*)Vs + dt*2048 + l15*128 + tV[0]);
            short8v bv1 = *(const short8v*)((const char*)Vs + dt*2048 + l15*128 + tV[1]);
            o0[dt] = __builtin_amdgcn_mfma_f32_16x16x32_bf16(a00, bv0, o0[dt], 0, 0, 0);
            o0[dt] = __builtin_amdgcn_mfma_f32_16x16x32_bf16(a01, bv1, o0[dt], 0, 0, 0);
            o1[dt] = __builtin_amdgcn_mfma_f32_16x16x32_bf16(a10, bv0, o1[dt], 0, 0, 0);
            o1[dt] = __builtin_amdgcn_mfma_f32_16x16x32_bf16(a11, bv1, o1[dt], 0, 0, 0);
        }
        __builtin_amdgcn_s_setprio(0);
        __syncthreads();

        if (t + 1 < NT) {
            #pragma unroll
            for (int j = 0; j < 3; ++j) {
                *(short8v*)((char*)Ks + kdst[j]) = kreg[j];
                *(short8v*)((char*)Vs + vdst[j]) = vreg[j];
            }
        }
        __syncthreads();
    }

    // ---- epilogue: unnormalized bf16 partials ----
    ushort* ob = opb + (((size_t)sc * BH + bh) * LQ + qt*QB + w*32) * HD;
    #pragma unroll
    for (int r = 0; r < 4; ++r) {
        #pragma unroll
        for (int dt = 0; dt < 6; ++dt) {
            ob[(size_t)(lg*4 + r) * HD + dt*16 + l15]      = f2bf(o0[dt][r]);
            ob[(size_t)(16 + lg*4 + r) * HD + dt*16 + l15] = f2bf(o1[dt][r]);
        }
    }
    if (lane < 16) {
        size_t mlrow = ((size_t)sc * BH + bh) * LQ + qt*QB + w*32 + lane;
        mlb[mlrow*2 + 0] = m_0;
        mlb[mlrow*2 + 1] = l_0;
        mlb[(mlrow + 16)*2 + 0] = m_1;
        mlb[(mlrow + 16)*2 + 1] = l_1;
    }
}

// merge KVS=4 bf16 partials -> ctx bf16 (B, LQ, 768); m,l in log2 domain
__global__ __launch_bounds__(256)
void combine(const ushort* __restrict__ opb, const float* __restrict__ mlb,
             ushort* __restrict__ ctx)
{
    const int NROW = BH * LQ;
    int idx = blockIdx.x * 256 + threadIdx.x;
    int row = idx / 12, seg = idx % 12;

    float m[KVS], lv[KVS];
    #pragma unroll
    for (int i = 0; i < KVS; ++i) {
        m[i]  = mlb[((size_t)i*NROW + row)*2 + 0];
        lv[i] = mlb[((size_t)i*NROW + row)*2 + 1];
    }
    float ms = m[0];
    #pragma unroll
    for (int i = 1; i < KVS; ++i) ms = fmaxf(ms, m[i]);
    float wsum = 0.f, wgt[KVS];
    #pragma unroll
    for (int i = 0; i < KVS; ++i) {
        wgt[i] = exp2hw(m[i] - ms);
        wsum += lv[i] * wgt[i];
    }
    float inv = 1.f / wsum;

    float acc[8] = {};
    #pragma unroll
    for (int i = 0; i < KVS; ++i) {
        uint4 v = *(const uint4*)&opb[((size_t)i*NROW + row)*HD + seg*8];
        uint vv[4] = {v.x, v.y, v.z, v.w};
        #pragma unroll
        for (int j2 = 0; j2 < 4; ++j2) {
            acc[j2*2+0] += bf2f((ushort)(vv[j2] & 0xffff)) * wgt[i];
            acc[j2*2+1] += bf2f((ushort)(vv[j2] >> 16))    * wgt[i];
        }
    }

    int bh = row / LQ, l = row % LQ;
    int b = bh >> 3, h = bh & 7;
    ushort* o = ctx + ((size_t)b * LQ + l) * DM + h * HD + seg*8;
    uint4 pk;
    pk.x = cvtpk(acc[0]*inv, acc[1]*inv);
    pk.y = cvtpk(acc[2]*inv, acc[3]*inv);
    pk.z = cvtpk(acc[4]*inv, acc[5]*inv);
    pk.w = cvtpk(acc[6]*inv, acc[7]*inv);
    *(uint4*)o = pk;
}

extern "C" void kernel_launch(void* const* d_in, const int* in_sizes, int n_in,
                              void* d_out, int out_size, void* d_ws, size_t ws_size,
                              hipStream_t stream)
{
    const float* query = (const float*)d_in[0];
    const float* key   = (const float*)d_in[1];
    const float* value = (const float*)d_in[2];
    const float* cq    = (const float*)d_in[3];
    const float* ck    = (const float*)d_in[4];
    const float* Wq    = (const float*)d_in[5];
    const float* bqv   = (const float*)d_in[6];
    const float* Wk    = (const float*)d_in[7];
    const float* bkv   = (const float*)d_in[8];
    const float* Wv    = (const float*)d_in[9];
    const float* bvv   = (const float*)d_in[10];
    const float* Wo    = (const float*)d_in[11];
    const float* bov   = (const float*)d_in[12];
    float* out = (float*)d_out;

    const size_t NQ = (size_t)BQ * LQ * DM;   // 3,145,728
    const size_t NK = (size_t)BQ * LK * DM;   // 12,582,912
    const size_t NP = (size_t)KVS * BH * LQ * HD;  // 12,582,912 partial elems

    ushort* wq  = (ushort*)d_ws;        // 4 weight matrices contiguous
    ushort* wk  = wq  + NW;
    ushort* wv  = wk  + NW;
    ushort* wo  = wv  + NW;
    ushort* qws = wo  + NW;             // q bf16 (B,H,LQ,96)
    ushort* kws = qws + NQ;             // k bf16 (B,H,LK,96)
    ushort* vtb = kws + NK;             // v^T bf16 (B,H,96,LK)
    ushort* opb = vtb + NK;             // bf16 partials
    ushort* ctx = opb + NP;             // ctx bf16 (B,LQ,768)
    float*  mlb = (float*)(ctx + NQ);   // KVS*BH*LQ*(m,l)
    // total ~94 MB

    wcvt<<<4*(NW/1024), 256, 0, stream>>>(Wq, Wk, Wv, Wo, wq);
    qkv_gemm<<<864, 256, 0, stream>>>(query, key, value, wq, wk, wv,
                                      bqv, bkv, bvv, cq, ck, qws, kws, vtb);
    attn_mfma<<<(LQ/QB) * BH * KVS, 256, 0, stream>>>(qws, kws, vtb, opb, mlb);
    combine<<<BH*LQ*12/256, 256, 0, stream>>>(opb, mlb, ctx);
    gemm_out<<<(BQ*LQ/64)*6, 256, 0, stream>>>(ctx, wo, bov, out);
}

// Round 16
// 159.848 us; speedup vs baseline: 1.1025x; 1.0744x over previous
//
#include <hip/hip_runtime.h>
#include <math.h>

#define DM 768
#define NH 8
#define HD 96
#define BQ 4
#define LQ 1024
#define LK 4096
#define BH (BQ*NH)
#define KVS 4              // kv-split factor
#define KC (LK/KVS)        // keys per chunk = 1024
#define NT (KC/64)         // 64-key tiles per block = 16
#define QB 128             // q-rows per block (32 per wave)
#define NW (DM*DM)

typedef unsigned short ushort;
typedef unsigned int uint;
typedef __attribute__((ext_vector_type(8))) short short8v;
typedef __attribute__((ext_vector_type(4))) float float4v;

// 1/sqrt(96) * log2(e)  (folded into Q projection)
#define QSCALE 0.14724444641f

static __device__ __forceinline__ ushort f2bf(float x) {
    union { float f; uint u; } c; c.f = x;
    uint u = c.u;
    u += ((u >> 16) & 1u) + 0x7fffu;   // RNE
    return (ushort)(u >> 16);
}

static __device__ __forceinline__ float bf2f(ushort x) {
    union { uint u; float f; } c; c.u = (uint)x << 16;
    return c.f;
}

static __device__ __forceinline__ uint cvtpk(float lo, float hi) {
    uint d;
    asm("v_cvt_pk_bf16_f32 %0, %1, %2" : "=v"(d) : "v"(lo), "v"(hi));
    return d;
}

static __device__ __forceinline__ float exp2hw(float x) {
#if __has_builtin(__builtin_amdgcn_exp2f)
    return __builtin_amdgcn_exp2f(x);
#else
    return __expf(x * 0.6931471805599453f);
#endif
}

static __device__ __forceinline__ void gload_lds16(const void* g, void* l) {
    __builtin_amdgcn_global_load_lds(
        (const __attribute__((address_space(1))) uint*)g,
        (__attribute__((address_space(3))) uint*)l, 16, 0, 0);
}

// weights fp32 -> bf16 (4 matrices into contiguous dst), 4 elems/thread
__global__ __launch_bounds__(256)
void wcvt(const float* __restrict__ w0, const float* __restrict__ w1,
          const float* __restrict__ w2, const float* __restrict__ w3,
          ushort* __restrict__ d)
{
    const int SEG = NW / 1024;           // 576 blocks per matrix
    int b = blockIdx.x;
    int wsel = b / SEG, ib = b % SEG;
    const float* s = (wsel == 0) ? w0 : (wsel == 1) ? w1 : (wsel == 2) ? w2 : w3;
    int i = ib * 256 + threadIdx.x;
    float4 v = ((const float4*)s)[i];
    uint2 o;
    o.x = (uint)f2bf(v.x) | ((uint)f2bf(v.y) << 16);
    o.y = (uint)f2bf(v.z) | ((uint)f2bf(v.w) << 16);
    ((uint2*)(d + (size_t)wsel * NW))[i] = o;
}

// Fused QKV projection GEMM, 128x256 block tile (wave = 64x128, acc 4x8).
// A: fp32 -> reg -> cvt_pk -> bf16 LDS (16 KB); B: bf16 gload_lds (32 KB).
// Simple single-buffered 2-barrier loop (R12's proven 94 us form).
// Segments: [0,96)=Q (RoPE), [96,480)=K (RoPE), [480,864)=V (transpose).
__global__ __launch_bounds__(256, 2)
void qkv_gemm(const float* __restrict__ qf, const float* __restrict__ kf,
              const float* __restrict__ vf,
              const ushort* __restrict__ wqb, const ushort* __restrict__ wkb,
              const ushort* __restrict__ wvb,
              const float* __restrict__ bq, const float* __restrict__ bk,
              const float* __restrict__ bv,
              const float* __restrict__ cq, const float* __restrict__ ck,
              ushort* __restrict__ qws, ushort* __restrict__ kws,
              ushort* __restrict__ vtb)
{
    // 48 KB: As bf16 [128][64] = [0,16384); Bs bf16 [256][64] = [16384,49152)
    __shared__ ushort Sh[24576];
    char* As = (char*)Sh;
    char* Bs = (char*)Sh + 16384;

    const int tid  = threadIdx.x;
    const int w    = tid >> 6;
    const int lane = tid & 63;
    const int l15  = lane & 15;
    const int lg   = lane >> 4;
    const int wm   = w >> 1, wn = w & 1;

    // segment decode (block-uniform)
    const int L = blockIdx.x;
    int seg, idx, Lshift, rpx;
    const float* X32; const ushort* Wbp; const float* bias; const float* coords;
    ushort* out; float oscale;
    if (L < 96)       { seg = 0; idx = L;       X32 = qf; Wbp = wqb; bias = bq; coords = cq; out = qws; Lshift = 10; rpx = 4;  oscale = QSCALE; }
    else if (L < 480) { seg = 1; idx = L - 96;  X32 = kf; Wbp = wkb; bias = bk; coords = ck; out = kws; Lshift = 12; rpx = 16; oscale = 1.0f; }
    else              { seg = 2; idx = L - 480; X32 = vf; Wbp = wvb; bias = bv; coords = 0;  out = vtb; Lshift = 12; rpx = 16; oscale = 1.0f; }

    const int xcd  = idx & 7;
    const int sq   = idx >> 3;
    const int col0 = (sq % 3) * 256;
    const int row0 = (xcd * rpx + sq / 3) * 128;

    float4v acc[4][8];
    #pragma unroll
    for (int m = 0; m < 4; ++m)
        #pragma unroll
        for (int n = 0; n < 8; ++n) acc[m][n] = (float4v)0.f;

    // A staging geometry (4 chunks, 16 KB, 2-bit XOR swizzle)
    int PA[4], rA[4], cA[4];
    #pragma unroll
    for (int c = 0; c < 4; ++c) {
        int P = ((w*4 + c) << 10) + lane*16;
        int lgc = P ^ (((P >> 9) & 3) << 5);
        PA[c] = P;
        rA[c] = lgc >> 7;
        cA[c] = (lgc & 127) >> 1;
    }
    // B staging geometry (8 chunks, 32 KB, same per-row swizzle)
    int PB[8], rB[8], cB[8];
    #pragma unroll
    for (int c = 0; c < 8; ++c) {
        int P = ((w*8 + c) << 10) + lane*16;
        int lgc = P ^ (((P >> 9) & 3) << 5);
        PB[c] = P;
        rB[c] = lgc >> 7;
        cB[c] = (lgc & 127) >> 1;
    }
    const float*  xb = X32 + (size_t)row0 * DM;
    const ushort* wb = Wbp + (size_t)col0 * DM;

    // fragment read offsets
    int offA[2][4], offB[2][8];
    #pragma unroll
    for (int kk = 0; kk < 2; ++kk) {
        #pragma unroll
        for (int m = 0; m < 4; ++m) {
            int byte = (wm*64 + m*16 + l15)*128 + kk*64 + lg*16;
            offA[kk][m] = byte ^ (((byte >> 9) & 3) << 5);
        }
        #pragma unroll
        for (int n = 0; n < 8; ++n) {
            int byte = (wn*128 + n*16 + l15)*128 + kk*64 + lg*16;
            offB[kk][n] = byte ^ (((byte >> 9) & 3) << 5);
        }
    }

    for (int kt = 0; kt < DM; kt += 64) {
        // B -> LDS via DMA
        #pragma unroll
        for (int c = 0; c < 8; ++c)
            gload_lds16(wb + (size_t)rB[c]*DM + kt + cB[c], Bs + PB[c]);
        // A: fp32 -> reg -> cvt -> bf16 LDS
        float4 fa[4], fb[4];
        #pragma unroll
        for (int c = 0; c < 4; ++c) {
            const float* src = xb + (size_t)rA[c]*DM + kt + cA[c];
            fa[c] = *(const float4*)src;
            fb[c] = *(const float4*)(src + 4);
        }
        #pragma unroll
        for (int c = 0; c < 4; ++c) {
            uint4 pk;
            pk.x = cvtpk(fa[c].x, fa[c].y);
            pk.y = cvtpk(fa[c].z, fa[c].w);
            pk.z = cvtpk(fb[c].x, fb[c].y);
            pk.w = cvtpk(fb[c].z, fb[c].w);
            *(uint4*)(As + PA[c]) = pk;
        }
        __syncthreads();
        #pragma unroll
        for (int kk = 0; kk < 2; ++kk) {
            short8v af[4], bfm[8];
            #pragma unroll
            for (int m = 0; m < 4; ++m)
                af[m] = *(const short8v*)(As + offA[kk][m]);
            #pragma unroll
            for (int n = 0; n < 8; ++n)
                bfm[n] = *(const short8v*)(Bs + offB[kk][n]);
            #pragma unroll
            for (int m = 0; m < 4; ++m)
                #pragma unroll
                for (int n = 0; n < 8; ++n)
                    acc[m][n] = __builtin_amdgcn_mfma_f32_16x16x32_bf16(af[m], bfm[n], acc[m][n], 0, 0, 0);
        }
        __syncthreads();
    }

    const int colbase = col0 + wn*128;   // 128-aligned -> RoPE F=0 always
    float bvv[8];
    #pragma unroll
    for (int nt = 0; nt < 8; ++nt) bvv[nt] = bias[colbase + nt*16 + l15];
    #pragma unroll
    for (int m = 0; m < 4; ++m)
        #pragma unroll
        for (int nt = 0; nt < 8; ++nt)
            #pragma unroll
            for (int r = 0; r < 4; ++r) acc[m][nt][r] += bvv[nt];

    if (seg < 2) {
        // RoPE: pair p = frags (2p, 2p+1); axis per 32-col chunk
        const float freq = exp2f(-(float)l15 * 0.83048202372184058696f);
        int ap[4];
        #pragma unroll
        for (int p = 0; p < 4; ++p) ap[p] = ((colbase >> 5) + p) % 3;
        #pragma unroll
        for (int m = 0; m < 4; ++m) {
            #pragma unroll
            for (int r = 0; r < 4; ++r) {
                int row = row0 + wm*64 + m*16 + lg*4 + r;
                const float* c3 = coords + (size_t)row * 3;
                #pragma unroll
                for (int p = 0; p < 4; ++p) {
                    float sn, cs;
                    __sincosf(c3[ap[p]] * freq, &sn, &cs);
                    float A_ = acc[m][2*p][r], B_ = acc[m][2*p+1][r];
                    acc[m][2*p][r]   = (A_*cs - B_*sn) * oscale;
                    acc[m][2*p+1][r] = (A_*sn + B_*cs) * oscale;
                }
            }
        }
        const int Lm1 = (1 << Lshift) - 1;
        int hh[8], tt[8];
        #pragma unroll
        for (int nt = 0; nt < 8; ++nt) {
            int j0 = colbase + nt*16;
            hh[nt] = j0 / HD;
            tt[nt] = j0 % HD + l15;
        }
        #pragma unroll
        for (int m = 0; m < 4; ++m)
            #pragma unroll
            for (int r = 0; r < 4; ++r) {
                int row = row0 + wm*64 + m*16 + lg*4 + r;
                int b = row >> Lshift, l = row & Lm1;
                #pragma unroll
                for (int nt = 0; nt < 8; ++nt)
                    out[(((size_t)b*NH + hh[nt]) << Lshift | l) * HD + tt[nt]] =
                        f2bf(acc[m][nt][r]);
            }
    } else {
        // V: re-transpose in two 128-col halves through first 32 KB of Sh
        #pragma unroll
        for (int h2 = 0; h2 < 2; ++h2) {
            __syncthreads();
            if (wn == h2) {
                #pragma unroll
                for (int m = 0; m < 4; ++m)
                    #pragma unroll
                    for (int nt = 0; nt < 8; ++nt)
                        #pragma unroll
                        for (int r = 0; r < 4; ++r) {
                            int c  = nt*16 + l15;                 // 0..127 within half
                            int ri = wm*64 + m*16 + lg*4 + r;     // 0..127
                            *(ushort*)((char*)Sh + c*256 + (((ri>>3) ^ (c&7))<<4) + (ri&7)*2)
                                = f2bf(acc[m][nt][r]);
                        }
            }
            __syncthreads();
            #pragma unroll
            for (int e = 0; e < 8; ++e) {
                int idx2 = tid + 256*e;
                int c = idx2 >> 4, r8 = idx2 & 15;
                uint4 val = *(const uint4*)((const char*)Sh + c*256 + ((r8 ^ (c&7))<<4));
                int j = col0 + h2*128 + c;
                int h = j / HD, t = j % HD;
                int row = row0 + r8*8;
                int b = row >> 12, l = row & (LK-1);
                *(uint4*)&out[(((size_t)b*NH + h)*HD + t)*LK + l] = val;
            }
        }
    }
}

// Output projection GEMM: ctx bf16 -> out fp32, 64x128 tile (24 KB LDS,
// grid 384 = 4 blocks/CU), XCD row-affinity. (R14's proven fast form.)
__global__ __launch_bounds__(256, 4)
void gemm_out(const ushort* __restrict__ X, const ushort* __restrict__ Wb,
              const float* __restrict__ bias, float* __restrict__ out)
{
    __shared__ ushort Sh[12288];     // As bf16 [64][64] = 8 KB; Bs [128][64] = 16 KB
    char* As = (char*)Sh;
    char* Bs = (char*)Sh + 8192;

    const int tid  = threadIdx.x;
    const int w    = tid >> 6;
    const int lane = tid & 63;
    const int l15  = lane & 15;
    const int lg   = lane >> 4;
    const int wm   = w >> 1, wn = w & 1;

    const int L    = blockIdx.x;
    const int xcd  = L & 7;
    const int sq   = L >> 3;
    const int col0 = (sq % 6) * 128;
    const int row0 = (xcd * 8 + sq / 6) * 64;

    float4v acc[2][4];
    #pragma unroll
    for (int m = 0; m < 2; ++m)
        #pragma unroll
        for (int n = 0; n < 4; ++n) acc[m][n] = (float4v)0.f;

    int PA[2], rA[2], cA[2];
    #pragma unroll
    for (int c = 0; c < 2; ++c) {
        int P = ((w*2 + c) << 10) + lane*16;
        int lgc = P ^ (((P >> 9) & 3) << 5);
        PA[c] = P;
        rA[c] = lgc >> 7;
        cA[c] = (lgc & 127) >> 1;
    }
    int PB[4], rB[4], cB[4];
    #pragma unroll
    for (int c = 0; c < 4; ++c) {
        int P = ((w*4 + c) << 10) + lane*16;
        int lgc = P ^ (((P >> 9) & 3) << 5);
        PB[c] = P;
        rB[c] = lgc >> 7;
        cB[c] = (lgc & 127) >> 1;
    }
    const ushort* xb = X  + (size_t)row0 * DM;
    const ushort* wb = Wb + (size_t)col0 * DM;

    int offA[2][2], offB[2][4];
    #pragma unroll
    for (int kk = 0; kk < 2; ++kk) {
        #pragma unroll
        for (int m = 0; m < 2; ++m) {
            int byte = (wm*32 + m*16 + l15)*128 + kk*64 + lg*16;
            offA[kk][m] = byte ^ (((byte >> 9) & 3) << 5);
        }
        #pragma unroll
        for (int n = 0; n < 4; ++n) {
            int byte = (wn*64 + n*16 + l15)*128 + kk*64 + lg*16;
            offB[kk][n] = byte ^ (((byte >> 9) & 3) << 5);
        }
    }

    for (int kt = 0; kt < DM; kt += 64) {
        #pragma unroll
        for (int c = 0; c < 2; ++c)
            gload_lds16(xb + (size_t)rA[c]*DM + kt + cA[c], As + PA[c]);
        #pragma unroll
        for (int c = 0; c < 4; ++c)
            gload_lds16(wb + (size_t)rB[c]*DM + kt + cB[c], Bs + PB[c]);
        __syncthreads();
        #pragma unroll
        for (int kk = 0; kk < 2; ++kk) {
            short8v af[2], bfm[4];
            #pragma unroll
            for (int m = 0; m < 2; ++m)
                af[m] = *(const short8v*)(As + offA[kk][m]);
            #pragma unroll
            for (int n = 0; n < 4; ++n)
                bfm[n] = *(const short8v*)(Bs + offB[kk][n]);
            #pragma unroll
            for (int m = 0; m < 2; ++m)
                #pragma unroll
                for (int n = 0; n < 4; ++n)
                    acc[m][n] = __builtin_amdgcn_mfma_f32_16x16x32_bf16(af[m], bfm[n], acc[m][n], 0, 0, 0);
        }
        __syncthreads();
    }

    const int colbase = col0 + wn*64;
    float bvv[4];
    #pragma unroll
    for (int nt = 0; nt < 4; ++nt) bvv[nt] = bias[colbase + nt*16 + l15];
    #pragma unroll
    for (int m = 0; m < 2; ++m)
        #pragma unroll
        for (int r = 0; r < 4; ++r) {
            int row = row0 + wm*32 + m*16 + lg*4 + r;
            #pragma unroll
            for (int nt = 0; nt < 4; ++nt)
                out[(size_t)row*DM + colbase + nt*16 + l15] = acc[m][nt][r] + bvv[nt];
        }
}

// MFMA flash attention, KV-split 4, swapped-QK^T, exp2-domain softmax.
// Block = 4 waves x 128 q-rows (wave owns 32 = 2 fragments); KVBLK=64.
// XCD decode keeps each (bh,sc) K/V chunk L2-resident. (Unchanged.)
__global__ __launch_bounds__(256, 2)
void attn_mfma(const ushort* __restrict__ q, const ushort* __restrict__ k,
               const ushort* __restrict__ vt, ushort* __restrict__ opb,
               float* __restrict__ mlb)
{
    __shared__ ushort Ks[64*128];     // 16 KB, slot^=(row&7)
    __shared__ ushort Vs[96*64];      // 12 KB, slot^=(row&7)
    __shared__ ushort PsT[4][32][72]; // 18 KB: [wave][q][key]

    const int tid  = threadIdx.x;
    const int w    = tid >> 6;
    const int lane = tid & 63;
    const int l15  = lane & 15;
    const int lg   = lane >> 4;

    const int L   = blockIdx.x;
    const int xcd = L & 7;
    const int s   = L >> 3;                 // 0..127
    const int pr  = xcd*16 + (s >> 3);      // 0..127
    const int qt  = s & 7;                  // 0..7
    const int bh  = pr & 31;
    const int sc  = pr >> 5;                // 0..3

    const ushort* qg = q  + ((size_t)bh * LQ + qt*QB + w*32 + l15) * HD;
    const ushort* kg = k  + ((size_t)bh * LK + (size_t)sc * KC) * HD;
    const ushort* vg = vt + (size_t)bh * HD * LK + (size_t)sc * KC;

    short8v aq0[3], aq1[3];
    #pragma unroll
    for (int dc = 0; dc < 3; ++dc) {
        aq0[dc] = *(const short8v*)(qg + dc*32 + lg*8);
        aq1[dc] = *(const short8v*)(qg + 16*HD + dc*32 + lg*8);
    }

    int kdst[3], ksrc[3], vdst[3], vsrc[3];
    #pragma unroll
    for (int j = 0; j < 3; ++j) {
        int c = tid + 256*j;
        int kr = c / 12, ks = c % 12;
        kdst[j] = kr*256 + ((ks ^ (kr & 7)) << 4);
        ksrc[j] = kr*HD + ks*8;
        int vr = c >> 3, vs = c & 7;
        vdst[j] = vr*128 + ((vs ^ (vr & 7)) << 4);
        vsrc[j] = vr*LK + vs*8;
    }
    int tK[3], tV[2];
    #pragma unroll
    for (int dc = 0; dc < 3; ++dc) tK[dc] = ((dc*4 + lg) ^ (l15 & 7)) << 4;
    #pragma unroll
    for (int h2 = 0; h2 < 2; ++h2)  tV[h2] = ((h2*4 + lg) ^ (l15 & 7)) << 4;

    float4v o0[6], o1[6];
    #pragma unroll
    for (int dt = 0; dt < 6; ++dt) { o0[dt] = (float4v)0.f; o1[dt] = (float4v)0.f; }
    float m_0 = -1e30f, l_0 = 0.f;
    float m_1 = -1e30f, l_1 = 0.f;

    short8v kreg[3], vreg[3];
    #pragma unroll
    for (int j = 0; j < 3; ++j) {
        kreg[j] = *(const short8v*)(kg + ksrc[j]);
        vreg[j] = *(const short8v*)(vg + vsrc[j]);
    }
    #pragma unroll
    for (int j = 0; j < 3; ++j) {
        *(short8v*)((char*)Ks + kdst[j]) = kreg[j];
        *(short8v*)((char*)Vs + vdst[j]) = vreg[j];
    }
    __syncthreads();

    for (int t = 0; t < NT; ++t) {
        if (t + 1 < NT) {
            const ushort* kn = kg + (size_t)(t+1)*64*HD;
            const ushort* vn = vg + (t+1)*64;
            #pragma unroll
            for (int j = 0; j < 3; ++j) {
                kreg[j] = *(const short8v*)(kn + ksrc[j]);
                vreg[j] = *(const short8v*)(vn + vsrc[j]);
            }
        }

        // ---- S^T = K Q^T ----
        float4v s0[4], s1[4];
        __builtin_amdgcn_s_setprio(1);
        #pragma unroll
        for (int nt = 0; nt < 4; ++nt) {
            s0[nt] = (float4v)0.f;
            s1[nt] = (float4v)0.f;
            #pragma unroll
            for (int dc = 0; dc < 3; ++dc) {
                short8v bk = *(const short8v*)((const char*)Ks + nt*4096 + l15*256 + tK[dc]);
                s0[nt] = __builtin_amdgcn_mfma_f32_16x16x32_bf16(bk, aq0[dc], s0[nt], 0, 0, 0);
                s1[nt] = __builtin_amdgcn_mfma_f32_16x16x32_bf16(bk, aq1[dc], s1[nt], 0, 0, 0);
            }
        }
        __builtin_amdgcn_s_setprio(0);

        // ---- online softmax (log2 domain) ----
        float mt0 = -1e30f, mt1 = -1e30f;
        #pragma unroll
        for (int nt = 0; nt < 4; ++nt)
            #pragma unroll
            for (int r = 0; r < 4; ++r) {
                mt0 = fmaxf(mt0, s0[nt][r]);
                mt1 = fmaxf(mt1, s1[nt][r]);
            }
        mt0 = fmaxf(mt0, __shfl_xor(mt0, 16, 64));
        mt0 = fmaxf(mt0, __shfl_xor(mt0, 32, 64));
        mt1 = fmaxf(mt1, __shfl_xor(mt1, 16, 64));
        mt1 = fmaxf(mt1, __shfl_xor(mt1, 32, 64));

        if (__any((mt0 > m_0 + 11.5f) || (mt1 > m_1 + 11.5f))) {
            float mn0 = fmaxf(m_0, mt0), mn1 = fmaxf(m_1, mt1);
            float a0 = exp2hw(m_0 - mn0), a1 = exp2hw(m_1 - mn1);
            m_0 = mn0; m_1 = mn1;
            l_0 *= a0;  l_1 *= a1;
            float al0[4], al1[4];
            #pragma unroll
            for (int r = 0; r < 4; ++r) {
                al0[r] = __shfl(a0, lg*4 + r, 64);
                al1[r] = __shfl(a1, lg*4 + r, 64);
            }
            #pragma unroll
            for (int dt = 0; dt < 6; ++dt)
                #pragma unroll
                for (int r = 0; r < 4; ++r) {
                    o0[dt][r] *= al0[r];
                    o1[dt][r] *= al1[r];
                }
        }

        float ps0 = 0.f, ps1 = 0.f;
        #pragma unroll
        for (int nt = 0; nt < 4; ++nt)
            #pragma unroll
            for (int r = 0; r < 4; ++r) {
                float p0 = exp2hw(s0[nt][r] - m_0);
                float p1 = exp2hw(s1[nt][r] - m_1);
                s0[nt][r] = p0; ps0 += p0;
                s1[nt][r] = p1; ps1 += p1;
            }
        ps0 += __shfl_xor(ps0, 16, 64);
        ps0 += __shfl_xor(ps0, 32, 64);
        ps1 += __shfl_xor(ps1, 16, 64);
        ps1 += __shfl_xor(ps1, 32, 64);
        l_0 += ps0;
        l_1 += ps1;

        // ---- pack P^T rows ----
        #pragma unroll
        for (int nt = 0; nt < 4; ++nt) {
            uint2 pk0, pk1;
            pk0.x = cvtpk(s0[nt][0], s0[nt][1]);
            pk0.y = cvtpk(s0[nt][2], s0[nt][3]);
            pk1.x = cvtpk(s1[nt][0], s1[nt][1]);
            pk1.y = cvtpk(s1[nt][2], s1[nt][3]);
            *(uint2*)&PsT[w][l15][nt*16 + lg*4]      = pk0;
            *(uint2*)&PsT[w][16 + l15][nt*16 + lg*4] = pk1;
        }

        // ---- O += P V ----
        short8v a00 = *(const short8v*)&PsT[w][l15][lg*8];
        short8v a01 = *(const short8v*)&PsT[w][l15][32 + lg*8];
        short8v a10 = *(const short8v*)&PsT[w][16 + l15][lg*8];
        short8v a11 = *(const short8v*)&PsT[w][16 + l15][32 + lg*8];
        __builtin_amdgcn_s_setprio(1);
        #pragma unroll
        for (int dt = 0; dt < 6; ++dt) {
            short8v bv0 = *(const short8v*)((const char*)Vs + dt*2048 + l15*128 + tV[0]);
            short8v bv1 = *(const short8v*)((const char*)Vs + dt*2048 + l15*128 + tV[1]);
            o0[dt] = __builtin_amdgcn_mfma_f32_16x16x32_bf16(a00, bv0, o0[dt], 0, 0, 0);
            o0[dt] = __builtin_amdgcn_mfma_f32_16x16x32_bf16(a01, bv1, o0[dt], 0, 0, 0);
            o1[dt] = __builtin_amdgcn_mfma_f32_16x16x32_bf16(a10, bv0, o1[dt], 0, 0, 0);
            o1[dt] = __builtin_amdgcn_mfma_f32_16x16x32_bf16(a11, bv1, o1[dt], 0, 0, 0);
        }
        __builtin_amdgcn_s_setprio(0);
        __syncthreads();

        if (t + 1 < NT) {
            #pragma unroll
            for (int j = 0; j < 3; ++j) {
                *(short8v*)((char*)Ks + kdst[j]) = kreg[j];
                *(short8v*)((char*)Vs + vdst[j]) = vreg[j];
            }
        }
        __syncthreads();
    }

    // ---- epilogue: unnormalized bf16 partials ----
    ushort* ob = opb + (((size_t)sc * BH + bh) * LQ + qt*QB + w*32) * HD;
    #pragma unroll
    for (int r = 0; r < 4; ++r) {
        #pragma unroll
        for (int dt = 0; dt < 6; ++dt) {
            ob[(size_t)(lg*4 + r) * HD + dt*16 + l15]      = f2bf(o0[dt][r]);
            ob[(size_t)(16 + lg*4 + r) * HD + dt*16 + l15] = f2bf(o1[dt][r]);
        }
    }
    if (lane < 16) {
        size_t mlrow = ((size_t)sc * BH + bh) * LQ + qt*QB + w*32 + lane;
        mlb[mlrow*2 + 0] = m_0;
        mlb[mlrow*2 + 1] = l_0;
        mlb[(mlrow + 16)*2 + 0] = m_1;
        mlb[(mlrow + 16)*2 + 1] = l_1;
    }
}

// merge KVS=4 bf16 partials -> ctx bf16 (B, LQ, 768); m,l in log2 domain
__global__ __launch_bounds__(256)
void combine(const ushort* __restrict__ opb, const float* __restrict__ mlb,
             ushort* __restrict__ ctx)
{
    const int NROW = BH * LQ;
    int idx = blockIdx.x * 256 + threadIdx.x;
    int row = idx / 12, seg = idx % 12;

    float m[KVS], lv[KVS];
    #pragma unroll
    for (int i = 0; i < KVS; ++i) {
        m[i]  = mlb[((size_t)i*NROW + row)*2 + 0];
        lv[i] = mlb[((size_t)i*NROW + row)*2 + 1];
    }
    float ms = m[0];
    #pragma unroll
    for (int i = 1; i < KVS; ++i) ms = fmaxf(ms, m[i]);
    float wsum = 0.f, wgt[KVS];
    #pragma unroll
    for (int i = 0; i < KVS; ++i) {
        wgt[i] = exp2hw(m[i] - ms);
        wsum += lv[i] * wgt[i];
    }
    float inv = 1.f / wsum;

    float acc[8] = {};
    #pragma unroll
    for (int i = 0; i < KVS; ++i) {
        uint4 v = *(const uint4*)&opb[((size_t)i*NROW + row)*HD + seg*8];
        uint vv[4] = {v.x, v.y, v.z, v.w};
        #pragma unroll
        for (int j2 = 0; j2 < 4; ++j2) {
            acc[j2*2+0] += bf2f((ushort)(vv[j2] & 0xffff)) * wgt[i];
            acc[j2*2+1] += bf2f((ushort)(vv[j2] >> 16))    * wgt[i];
        }
    }

    int bh = row / LQ, l = row % LQ;
    int b = bh >> 3, h = bh & 7;
    ushort* o = ctx + ((size_t)b * LQ + l) * DM + h * HD + seg*8;
    uint4 pk;
    pk.x = cvtpk(acc[0]*inv, acc[1]*inv);
    pk.y = cvtpk(acc[2]*inv, acc[3]*inv);
    pk.z = cvtpk(acc[4]*inv, acc[5]*inv);
    pk.w = cvtpk(acc[6]*inv, acc[7]*inv);
    *(uint4*)o = pk;
}

extern "C" void kernel_launch(void* const* d_in, const int* in_sizes, int n_in,
                              void* d_out, int out_size, void* d_ws, size_t ws_size,
                              hipStream_t stream)
{
    const float* query = (const float*)d_in[0];
    const float* key   = (const float*)d_in[1];
    const float* value = (const float*)d_in[2];
    const float* cq    = (const float*)d_in[3];
    const float* ck    = (const float*)d_in[4];
    const float* Wq    = (const float*)d_in[5];
    const float* bqv   = (const float*)d_in[6];
    const float* Wk    = (const float*)d_in[7];
    const float* bkv   = (const float*)d_in[8];
    const float* Wv    = (const float*)d_in[9];
    const float* bvv   = (const float*)d_in[10];
    const float* Wo    = (const float*)d_in[11];
    const float* bov   = (const float*)d_in[12];
    float* out = (float*)d_out;

    const size_t NQ = (size_t)BQ * LQ * DM;   // 3,145,728
    const size_t NK = (size_t)BQ * LK * DM;   // 12,582,912
    const size_t NP = (size_t)KVS * BH * LQ * HD;  // 12,582,912 partial elems

    ushort* wq  = (ushort*)d_ws;        // 4 weight matrices contiguous
    ushort* wk  = wq  + NW;
    ushort* wv  = wk  + NW;
    ushort* wo  = wv  + NW;
    ushort* qws = wo  + NW;             // q bf16 (B,H,LQ,96)
    ushort* kws = qws + NQ;             // k bf16 (B,H,LK,96)
    ushort* vtb = kws + NK;             // v^T bf16 (B,H,96,LK)
    ushort* opb = vtb + NK;             // bf16 partials
    ushort* ctx = opb + NP;             // ctx bf16 (B,LQ,768)
    float*  mlb = (float*)(ctx + NQ);   // KVS*BH*LQ*(m,l)
    // total ~94 MB

    wcvt<<<4*(NW/1024), 256, 0, stream>>>(Wq, Wk, Wv, Wo, wq);
    qkv_gemm<<<864, 256, 0, stream>>>(query, key, value, wq, wk, wv,
                                      bqv, bkv, bvv, cq, ck, qws, kws, vtb);
    attn_mfma<<<(LQ/QB) * BH * KVS, 256, 0, stream>>>(qws, kws, vtb, opb, mlb);
    combine<<<BH*LQ*12/256, 256, 0, stream>>>(opb, mlb, ctx);
    gemm_out<<<(BQ*LQ/64)*6, 256, 0, stream>>>(ctx, wo, bov, out);
}